// Round 1
// baseline (1930.275 us; speedup 1.0000x reference)
//
#include <hip/hip_runtime.h>
#include <math.h>

// Problem constants (match reference)
constexpr int Bb  = 4;
constexpr int Ss  = 2048;
constexpr int Dd  = 1024;
constexpr int Hh  = 16;
constexpr int DHh = 64;
constexpr int Cc  = 64;            // chunk length
constexpr int NCc = Ss / Cc;       // 32 chunks
constexpr float EPSf = 1e-6f;

// ---------------------------------------------------------------------------
// fp32 tiled GEMM: out[M,N] = A[M,K] @ W[K,N], optional phi(x)=elu(x)+1
// 64x64 tile, BK=16, 256 threads, 4x4 per thread.
// ---------------------------------------------------------------------------
constexpr int GM = 64, GN = 64, GK = 16;

__global__ __launch_bounds__(256)
void gemm_phi_f32(const float* __restrict__ A, const float* __restrict__ W,
                  float* __restrict__ out, int M, int N, int Kd, int apply_phi) {
    __shared__ float As[GK][GM + 4];   // [k][m], +4 pad keeps rows 16B aligned
    __shared__ float Bs[GK][GN + 4];   // [k][n]
    const int tid = threadIdx.x;
    const int ty = tid >> 4;           // 0..15
    const int tx = tid & 15;           // 0..15
    const int row0 = blockIdx.y * GM;
    const int col0 = blockIdx.x * GN;

    float acc[4][4];
#pragma unroll
    for (int i = 0; i < 4; ++i)
#pragma unroll
        for (int j = 0; j < 4; ++j) acc[i][j] = 0.f;

    const int ar = tid >> 2;           // 0..63  (A tile row)
    const int ac = (tid & 3) << 2;     // 0,4,8,12 (A tile k-col)
    const int wr = tid >> 4;           // 0..15  (W tile k-row)
    const int wc = (tid & 15) << 2;    // 0..60  (W tile n-col)

    for (int kt = 0; kt < Kd; kt += GK) {
        float4 av = *reinterpret_cast<const float4*>(A + (size_t)(row0 + ar) * Kd + kt + ac);
        float4 wv = *reinterpret_cast<const float4*>(W + (size_t)(kt + wr) * N + col0 + wc);
        As[ac + 0][ar] = av.x;
        As[ac + 1][ar] = av.y;
        As[ac + 2][ar] = av.z;
        As[ac + 3][ar] = av.w;
        *reinterpret_cast<float4*>(&Bs[wr][wc]) = wv;
        __syncthreads();
#pragma unroll
        for (int k = 0; k < GK; ++k) {
            float4 a4 = *reinterpret_cast<const float4*>(&As[k][ty << 2]);
            float4 b4 = *reinterpret_cast<const float4*>(&Bs[k][tx << 2]);
            float a[4] = {a4.x, a4.y, a4.z, a4.w};
            float b[4] = {b4.x, b4.y, b4.z, b4.w};
#pragma unroll
            for (int i = 0; i < 4; ++i)
#pragma unroll
                for (int j = 0; j < 4; ++j) acc[i][j] = fmaf(a[i], b[j], acc[i][j]);
        }
        __syncthreads();
    }

#pragma unroll
    for (int i = 0; i < 4; ++i) {
        const size_t r = (size_t)(row0 + (ty << 2) + i);
        float4 o;
        float v0 = acc[i][0], v1 = acc[i][1], v2 = acc[i][2], v3 = acc[i][3];
        if (apply_phi) {
            v0 = (v0 > 0.f) ? (v0 + 1.f) : __expf(v0);
            v1 = (v1 > 0.f) ? (v1 + 1.f) : __expf(v1);
            v2 = (v2 > 0.f) ? (v2 + 1.f) : __expf(v2);
            v3 = (v3 > 0.f) ? (v3 + 1.f) : __expf(v3);
        }
        o.x = v0; o.y = v1; o.z = v2; o.w = v3;
        *reinterpret_cast<float4*>(out + r * N + col0 + (tx << 2)) = o;
    }
}

// ---------------------------------------------------------------------------
// Kernel B: per-chunk summaries.  For each (b,h,chunk):
//   CS[bh,c] = K_chunk^T @ V_chunk   (DH x DH)
//   CZ[bh,c] = sum_j k_j             (DH)
// grid = B*H*NC blocks of 256.
// ---------------------------------------------------------------------------
__global__ __launch_bounds__(256)
void chunk_sums(const float* __restrict__ Kp, const float* __restrict__ Vp,
                float* __restrict__ CS, float* __restrict__ CZ) {
    const int blk = blockIdx.x;
    const int c  = blk % NCc;
    const int bh = blk / NCc;
    const int b  = bh / Hh;
    const int h  = bh % Hh;
    const int tid = threadIdx.x;
    const int s0 = c * Cc;

    __shared__ float Ks[Cc * DHh];   // 16 KB, unpadded (float4-friendly)
    __shared__ float Vs[Cc * DHh];

    const size_t rowbase = ((size_t)b * Ss + s0) * Dd + (size_t)h * DHh;
#pragma unroll
    for (int it = 0; it < 4; ++it) {
        int idx = tid + it * 256;            // float4 index 0..1023
        int r   = idx >> 4;                  // row 0..63
        int c4  = (idx & 15) << 2;           // col 0..60
        float4 kv = *reinterpret_cast<const float4*>(Kp + rowbase + (size_t)r * Dd + c4);
        float4 vv = *reinterpret_cast<const float4*>(Vp + rowbase + (size_t)r * Dd + c4);
        reinterpret_cast<float4*>(Ks)[idx] = kv;
        reinterpret_cast<float4*>(Vs)[idx] = vv;
    }
    __syncthreads();

    const int e  = tid >> 2;                 // 0..63  (K column)
    const int d0 = (tid & 3) << 4;           // 0,16,32,48 (V column block)
    float acc[16];
#pragma unroll
    for (int dd = 0; dd < 16; ++dd) acc[dd] = 0.f;

    for (int j = 0; j < Cc; ++j) {
        float kv = Ks[j * DHh + e];
#pragma unroll
        for (int q = 0; q < 4; ++q) {
            float4 v4 = *reinterpret_cast<const float4*>(&Vs[j * DHh + d0 + (q << 2)]);
            acc[q * 4 + 0] = fmaf(kv, v4.x, acc[q * 4 + 0]);
            acc[q * 4 + 1] = fmaf(kv, v4.y, acc[q * 4 + 1]);
            acc[q * 4 + 2] = fmaf(kv, v4.z, acc[q * 4 + 2]);
            acc[q * 4 + 3] = fmaf(kv, v4.w, acc[q * 4 + 3]);
        }
    }

    float* csbase = CS + ((size_t)bh * NCc + c) * (DHh * DHh);
#pragma unroll
    for (int q = 0; q < 4; ++q) {
        float4 o = make_float4(acc[q * 4 + 0], acc[q * 4 + 1], acc[q * 4 + 2], acc[q * 4 + 3]);
        *reinterpret_cast<float4*>(csbase + e * DHh + d0 + (q << 2)) = o;
    }

    if (tid < DHh) {
        float z = 0.f;
        for (int j = 0; j < Cc; ++j) z += Ks[j * DHh + tid];
        CZ[((size_t)bh * NCc + c) * DHh + tid] = z;
    }
}

// ---------------------------------------------------------------------------
// Kernel C: in-place exclusive prefix scan over chunks, per (b,h).
// grid = B*H blocks of 256; each thread owns 16 floats of the 4096 state.
// ---------------------------------------------------------------------------
__global__ __launch_bounds__(256)
void chunk_scan(float* __restrict__ CS, float* __restrict__ CZ) {
    const int bh  = blockIdx.x;
    const int tid = threadIdx.x;
    float4 acc[4];
#pragma unroll
    for (int q = 0; q < 4; ++q) acc[q] = make_float4(0.f, 0.f, 0.f, 0.f);
    float accz = 0.f;

    for (int c = 0; c < NCc; ++c) {
        float4* base = reinterpret_cast<float4*>(CS + ((size_t)bh * NCc + c) * (DHh * DHh));
#pragma unroll
        for (int q = 0; q < 4; ++q) {
            float4 cur = base[tid + q * 256];
            base[tid + q * 256] = acc[q];
            acc[q].x += cur.x; acc[q].y += cur.y; acc[q].z += cur.z; acc[q].w += cur.w;
        }
        if (tid < DHh) {
            float* pz = CZ + ((size_t)bh * NCc + c) * DHh + tid;
            float cur = *pz;
            *pz = accz;
            accz += cur;
        }
    }
}

// ---------------------------------------------------------------------------
// Kernel D: per-chunk output.
//   A = mask(Q K^T);  num = A@V + Q@S_prev;  den = Q.z_prev + rowsum(A)
//   O = num / (den + eps)
// grid = B*H*NC blocks of 256.
// ---------------------------------------------------------------------------
__global__ __launch_bounds__(256)
void chunk_out(const float* __restrict__ Qp, const float* __restrict__ Kp,
               const float* __restrict__ Vp, const float* __restrict__ CS,
               const float* __restrict__ CZ, float* __restrict__ Op) {
    const int blk = blockIdx.x;
    const int c  = blk % NCc;
    const int bh = blk / NCc;
    const int b  = bh / Hh;
    const int h  = bh % Hh;
    const int tid = threadIdx.x;
    const int s0 = c * Cc;

    __shared__ float bufQ[Cc][DHh + 1];   // padded: conflict-free column reads
    __shared__ float bufK[Cc][DHh + 1];   // holds K, then A
    __shared__ float bufV[Cc][DHh + 1];   // holds S_prev, then V
    __shared__ float zs[DHh];
    __shared__ float denp[Cc][4];

    const size_t rowbase = ((size_t)b * Ss + s0) * Dd + (size_t)h * DHh;
    const float* csbase = CS + ((size_t)bh * NCc + c) * (DHh * DHh);

#pragma unroll
    for (int it = 0; it < 4; ++it) {
        int idx = tid + it * 256;
        int r   = idx >> 4;
        int c4  = (idx & 15) << 2;
        float4 qv = *reinterpret_cast<const float4*>(Qp + rowbase + (size_t)r * Dd + c4);
        float4 kv = *reinterpret_cast<const float4*>(Kp + rowbase + (size_t)r * Dd + c4);
        float4 sv = *reinterpret_cast<const float4*>(csbase + (size_t)idx * 4);
        bufQ[r][c4 + 0] = qv.x; bufQ[r][c4 + 1] = qv.y; bufQ[r][c4 + 2] = qv.z; bufQ[r][c4 + 3] = qv.w;
        bufK[r][c4 + 0] = kv.x; bufK[r][c4 + 1] = kv.y; bufK[r][c4 + 2] = kv.z; bufK[r][c4 + 3] = kv.w;
        bufV[r][c4 + 0] = sv.x; bufV[r][c4 + 1] = sv.y; bufV[r][c4 + 2] = sv.z; bufV[r][c4 + 3] = sv.w;
    }
    if (tid < DHh) zs[tid] = CZ[((size_t)bh * NCc + c) * DHh + tid];
    __syncthreads();

    const int i  = tid >> 2;          // output row within chunk
    const int tx = tid & 3;
    const int j0 = tx << 4;           // 16-col block (for both A-cols and V-cols)

    float Areg[16];
    float acc[16];
#pragma unroll
    for (int dd = 0; dd < 16; ++dd) acc[dd] = 0.f;

    // A[i][j] = q_i . k_j, causal mask (j <= i)
#pragma unroll
    for (int jj = 0; jj < 16; ++jj) {
        int j = j0 + jj;
        float s = 0.f;
        for (int e = 0; e < DHh; ++e) s = fmaf(bufQ[i][e], bufK[j][e], s);
        Areg[jj] = (j <= i) ? s : 0.f;
    }
    // inter-chunk: acc += Q[i][:] @ S_prev[:, j0..j0+15]
    for (int e = 0; e < DHh; ++e) {
        float qv = bufQ[i][e];
#pragma unroll
        for (int dd = 0; dd < 16; ++dd) acc[dd] = fmaf(qv, bufV[e][j0 + dd], acc[dd]);
    }
    // den pieces
    float deni = 0.f;
    for (int e = 0; e < DHh; ++e) deni = fmaf(bufQ[i][e], zs[e], deni);
    float part = 0.f;
#pragma unroll
    for (int jj = 0; jj < 16; ++jj) part += Areg[jj];

    __syncthreads();   // all reads of K / S_prev complete

    // A -> bufK; V -> bufV
#pragma unroll
    for (int jj = 0; jj < 16; ++jj) bufK[i][j0 + jj] = Areg[jj];
    denp[i][tx] = part;
#pragma unroll
    for (int it = 0; it < 4; ++it) {
        int idx = tid + it * 256;
        int r   = idx >> 4;
        int c4  = (idx & 15) << 2;
        float4 vv = *reinterpret_cast<const float4*>(Vp + rowbase + (size_t)r * Dd + c4);
        bufV[r][c4 + 0] = vv.x; bufV[r][c4 + 1] = vv.y; bufV[r][c4 + 2] = vv.z; bufV[r][c4 + 3] = vv.w;
    }
    __syncthreads();

    const float den = deni + denp[i][0] + denp[i][1] + denp[i][2] + denp[i][3] + EPSf;
    // intra-chunk: acc += A[i][:] @ V[:, j0..j0+15]
    for (int j = 0; j < Cc; ++j) {
        float a = bufK[i][j];
#pragma unroll
        for (int dd = 0; dd < 16; ++dd) acc[dd] = fmaf(a, bufV[j][j0 + dd], acc[dd]);
    }

    const float inv = 1.0f / den;
#pragma unroll
    for (int q = 0; q < 4; ++q) {
        float4 o = make_float4(acc[q * 4 + 0] * inv, acc[q * 4 + 1] * inv,
                               acc[q * 4 + 2] * inv, acc[q * 4 + 3] * inv);
        *reinterpret_cast<float4*>(Op + rowbase + (size_t)i * Dd + j0 + (q << 2)) = o;
    }
}

// ---------------------------------------------------------------------------
extern "C" void kernel_launch(void* const* d_in, const int* in_sizes, int n_in,
                              void* d_out, int out_size, void* d_ws, size_t ws_size,
                              hipStream_t stream) {
    const float* x  = (const float*)d_in[0];
    const float* Wq = (const float*)d_in[1];
    const float* Wk = (const float*)d_in[2];
    const float* Wv = (const float*)d_in[3];
    const float* Wo = (const float*)d_in[4];

    const size_t NQKV = (size_t)Bb * Ss * Dd;           // 8388608 floats
    float* ws = (float*)d_ws;
    float* Kb = ws;                                     // 32 MB
    float* Vb = Kb + NQKV;                              // 32 MB
    float* Ob = Vb + NQKV;                              // 32 MB
    float* CS = Ob + NQKV;                              // B*H*NC*DH*DH = 32 MB
    float* CZ = CS + (size_t)Bb * Hh * NCc * DHh * DHh; // 0.5 MB
    float* Qb = (float*)d_out;  // Q lives in d_out; fully consumed before final GEMM

    const int M = Bb * Ss;      // 8192
    const int N = Dd;           // 1024
    const int Kd = Dd;          // 1024
    dim3 ggrid(N / GN, M / GM); // (16, 128)

    // projections
    gemm_phi_f32<<<ggrid, 256, 0, stream>>>(x, Wq, Qb, M, N, Kd, 1);
    gemm_phi_f32<<<ggrid, 256, 0, stream>>>(x, Wk, Kb, M, N, Kd, 1);
    gemm_phi_f32<<<ggrid, 256, 0, stream>>>(x, Wv, Vb, M, N, Kd, 0);

    // chunked linear attention
    chunk_sums<<<Bb * Hh * NCc, 256, 0, stream>>>(Kb, Vb, CS, CZ);
    chunk_scan<<<Bb * Hh, 256, 0, stream>>>(CS, CZ);
    chunk_out<<<Bb * Hh * NCc, 256, 0, stream>>>(Qb, Kb, Vb, CS, CZ, Ob);

    // output projection (overwrites d_out)
    gemm_phi_f32<<<ggrid, 256, 0, stream>>>(Ob, Wo, (float*)d_out, M, N, Kd, 0);
}

// Round 2
// 286.179 us; speedup vs baseline: 6.7450x; 6.7450x over previous
//
#include <hip/hip_runtime.h>
#include <hip/hip_bf16.h>
#include <math.h>

// Problem constants
constexpr int Bb  = 4;
constexpr int Ss  = 2048;
constexpr int Dd  = 1024;
constexpr int Hh  = 16;
constexpr int DHh = 64;
constexpr int Cc  = 64;            // chunk length
constexpr int NCc = Ss / Cc;       // 32 chunks
constexpr int Mm  = Bb * Ss;       // 8192 rows
constexpr float EPSf = 1e-6f;

typedef __attribute__((ext_vector_type(8))) short bf16x8;
typedef __attribute__((ext_vector_type(4))) float f32x4;
typedef __attribute__((ext_vector_type(8))) unsigned short u16x8;

__device__ __forceinline__ float bf2f(unsigned short u) {
    return __uint_as_float((unsigned)u << 16);
}
__device__ __forceinline__ unsigned short f2bf(float f) {
    unsigned u = __float_as_uint(f);
    unsigned r = u + 0x7fff + ((u >> 16) & 1);   // RNE
    return (unsigned short)(r >> 16);
}

// ---------------------------------------------------------------------------
// cast fp32 -> bf16, 8 elems/thread
// ---------------------------------------------------------------------------
__global__ __launch_bounds__(256)
void cast_bf16(const float* __restrict__ in, unsigned short* __restrict__ out, int n8) {
    int i = blockIdx.x * 256 + threadIdx.x;
    if (i >= n8) return;
    const float4* p = reinterpret_cast<const float4*>(in) + (size_t)i * 2;
    float4 a = p[0], b = p[1];
    u16x8 o;
    o[0] = f2bf(a.x); o[1] = f2bf(a.y); o[2] = f2bf(a.z); o[3] = f2bf(a.w);
    o[4] = f2bf(b.x); o[5] = f2bf(b.y); o[6] = f2bf(b.z); o[7] = f2bf(b.w);
    *(reinterpret_cast<u16x8*>(out) + i) = o;
}

// ---------------------------------------------------------------------------
// W [K][N] fp32 -> WT bf16 [N][K]; 4 weights selected by blockIdx.z
// ---------------------------------------------------------------------------
__global__ __launch_bounds__(256)
void transpose_cast_w(const float* __restrict__ W0, const float* __restrict__ W1,
                      const float* __restrict__ W2, const float* __restrict__ W3,
                      unsigned short* __restrict__ WT) {
    const float* W = (blockIdx.z == 0) ? W0 : (blockIdx.z == 1) ? W1
                     : (blockIdx.z == 2) ? W2 : W3;
    unsigned short* T = WT + (size_t)blockIdx.z * Dd * Dd;
    __shared__ float t[64][65];
    const int r0 = blockIdx.y * 64, c0 = blockIdx.x * 64;
    const int tid = threadIdx.x;
    const int lr = tid >> 4, lc4 = (tid & 15) * 4;
#pragma unroll
    for (int it = 0; it < 4; ++it) {
        int row = lr + it * 16;
        float4 v = *reinterpret_cast<const float4*>(W + (size_t)(r0 + row) * Dd + c0 + lc4);
        t[row][lc4 + 0] = v.x; t[row][lc4 + 1] = v.y;
        t[row][lc4 + 2] = v.z; t[row][lc4 + 3] = v.w;
    }
    __syncthreads();
#pragma unroll
    for (int it = 0; it < 4; ++it) {
        int col = lr + it * 16;     // tile col -> T row
        ushort4 o;
        o.x = f2bf(t[lc4 + 0][col]); o.y = f2bf(t[lc4 + 1][col]);
        o.z = f2bf(t[lc4 + 2][col]); o.w = f2bf(t[lc4 + 3][col]);
        *reinterpret_cast<ushort4*>(T + (size_t)(c0 + col) * Dd + r0 + lc4) = o;
    }
}

// ---------------------------------------------------------------------------
// bf16 MFMA GEMM (m97 structure): out[M,N] = A[M,K] @ BT[N,K]^T
// 128x128 tile, BK=32, 4 waves (2x2), 4x4 16x16x32 fragments per wave.
// MODE: bit0 = apply phi (elu+1), bit1 = bf16 output (else fp32)
// ---------------------------------------------------------------------------
template<int MODE>
__global__ __launch_bounds__(256)
void gemm_bf16mfma(const unsigned short* __restrict__ A, const unsigned short* __restrict__ BT,
                   float* __restrict__ outF, unsigned short* __restrict__ outB) {
    constexpr int Kd = 1024, Nn = 1024;
    __shared__ __align__(16) unsigned short As[128 * 32];
    __shared__ __align__(16) unsigned short Bs[128 * 32];
    const int tid  = threadIdx.x;
    const int lane = tid & 63;
    const int row0 = blockIdx.y * 128;
    const int col0 = blockIdx.x * 128;
    const int wr = ((tid >> 6) >> 1) * 64;   // wave row offset
    const int wc = ((tid >> 6) & 1) * 64;    // wave col offset
    const int fr = lane & 15;
    const int fk = (lane >> 4) * 8;

    f32x4 acc[4][4];
#pragma unroll
    for (int mf = 0; mf < 4; ++mf)
#pragma unroll
        for (int nf = 0; nf < 4; ++nf) acc[mf][nf] = (f32x4){0.f, 0.f, 0.f, 0.f};

    for (int kt = 0; kt < Kd; kt += 32) {
        // stage: 512 16B segments per matrix, 2 per thread
#pragma unroll
        for (int s = 0; s < 2; ++s) {
            int seg = tid + s * 256;
            int r = seg >> 2, c8 = (seg & 3) * 8;
            __builtin_amdgcn_global_load_lds(
                (const __attribute__((address_space(1))) void*)(A + (size_t)(row0 + r) * Kd + kt + c8),
                (__attribute__((address_space(3))) void*)(As + seg * 8), 16, 0, 0);
            __builtin_amdgcn_global_load_lds(
                (const __attribute__((address_space(1))) void*)(BT + (size_t)(col0 + r) * Kd + kt + c8),
                (__attribute__((address_space(3))) void*)(Bs + seg * 8), 16, 0, 0);
        }
        __syncthreads();
        bf16x8 af[4], bfv[4];
#pragma unroll
        for (int mf = 0; mf < 4; ++mf)
            af[mf] = *reinterpret_cast<const bf16x8*>(As + (wr + mf * 16 + fr) * 32 + fk);
#pragma unroll
        for (int nf = 0; nf < 4; ++nf)
            bfv[nf] = *reinterpret_cast<const bf16x8*>(Bs + (wc + nf * 16 + fr) * 32 + fk);
#pragma unroll
        for (int mf = 0; mf < 4; ++mf)
#pragma unroll
            for (int nf = 0; nf < 4; ++nf)
                acc[mf][nf] = __builtin_amdgcn_mfma_f32_16x16x32_bf16(af[mf], bfv[nf], acc[mf][nf], 0, 0, 0);
        __syncthreads();
    }

    // epilogue: D[row=(lane>>4)*4+r][col=lane&15] per fragment
#pragma unroll
    for (int mf = 0; mf < 4; ++mf) {
#pragma unroll
        for (int nf = 0; nf < 4; ++nf) {
#pragma unroll
            for (int r = 0; r < 4; ++r) {
                int orow = row0 + wr + mf * 16 + (lane >> 4) * 4 + r;
                int ocol = col0 + wc + nf * 16 + fr;
                float v = acc[mf][nf][r];
                if (MODE & 1) v = (v > 0.f) ? (v + 1.f) : __expf(v);
                if (MODE & 2) outB[(size_t)orow * Nn + ocol] = f2bf(v);
                else          outF[(size_t)orow * Nn + ocol] = v;
            }
        }
    }
}

// ---------------------------------------------------------------------------
// per-chunk summaries: CS = K^T V (fp32 from bf16 inputs), CZ = sum k
// ---------------------------------------------------------------------------
__global__ __launch_bounds__(256)
void chunk_sums(const unsigned short* __restrict__ Kp, const unsigned short* __restrict__ Vp,
                float* __restrict__ CS, float* __restrict__ CZ) {
    const int blk = blockIdx.x;
    const int c  = blk & (NCc - 1);
    const int bh = blk >> 5;
    const int b  = bh >> 4;
    const int h  = bh & 15;
    const int tid = threadIdx.x;
    const int s0 = c * Cc;

    __shared__ float Ks[Cc * DHh];
    __shared__ float Vs[Cc * DHh];

    const size_t rowbase = ((size_t)b * Ss + s0) * Dd + (size_t)h * DHh;
#pragma unroll
    for (int it = 0; it < 2; ++it) {
        int idx = tid + it * 256;            // 0..511 8-elem chunks
        int r = idx >> 3, c8 = (idx & 7) * 8;
        u16x8 kv = *reinterpret_cast<const u16x8*>(Kp + rowbase + (size_t)r * Dd + c8);
        u16x8 vv = *reinterpret_cast<const u16x8*>(Vp + rowbase + (size_t)r * Dd + c8);
#pragma unroll
        for (int q = 0; q < 8; ++q) {
            Ks[r * DHh + c8 + q] = bf2f(kv[q]);
            Vs[r * DHh + c8 + q] = bf2f(vv[q]);
        }
    }
    __syncthreads();

    const int e  = tid >> 2;
    const int d0 = (tid & 3) << 4;
    float acc[16];
#pragma unroll
    for (int dd = 0; dd < 16; ++dd) acc[dd] = 0.f;

#pragma unroll 4
    for (int j = 0; j < Cc; ++j) {
        float kv = Ks[j * DHh + e];
#pragma unroll
        for (int q = 0; q < 4; ++q) {
            float4 v4 = *reinterpret_cast<const float4*>(&Vs[j * DHh + d0 + (q << 2)]);
            acc[q * 4 + 0] = fmaf(kv, v4.x, acc[q * 4 + 0]);
            acc[q * 4 + 1] = fmaf(kv, v4.y, acc[q * 4 + 1]);
            acc[q * 4 + 2] = fmaf(kv, v4.z, acc[q * 4 + 2]);
            acc[q * 4 + 3] = fmaf(kv, v4.w, acc[q * 4 + 3]);
        }
    }

    float* csbase = CS + ((size_t)bh * NCc + c) * (DHh * DHh);
#pragma unroll
    for (int q = 0; q < 4; ++q) {
        float4 o = make_float4(acc[q * 4 + 0], acc[q * 4 + 1], acc[q * 4 + 2], acc[q * 4 + 3]);
        *reinterpret_cast<float4*>(csbase + e * DHh + d0 + (q << 2)) = o;
    }

    if (tid < DHh) {
        float z = 0.f;
        for (int j = 0; j < Cc; ++j) z += Ks[j * DHh + tid];
        CZ[((size_t)bh * NCc + c) * DHh + tid] = z;
    }
}

// ---------------------------------------------------------------------------
// exclusive prefix scan over chunks per (b,h)
// ---------------------------------------------------------------------------
__global__ __launch_bounds__(256)
void chunk_scan(float* __restrict__ CS, float* __restrict__ CZ) {
    const int bh  = blockIdx.x;
    const int tid = threadIdx.x;
    float4 acc[4];
#pragma unroll
    for (int q = 0; q < 4; ++q) acc[q] = make_float4(0.f, 0.f, 0.f, 0.f);
    float accz = 0.f;

    for (int c = 0; c < NCc; ++c) {
        float4* base = reinterpret_cast<float4*>(CS + ((size_t)bh * NCc + c) * (DHh * DHh));
#pragma unroll
        for (int q = 0; q < 4; ++q) {
            float4 cur = base[tid + q * 256];
            base[tid + q * 256] = acc[q];
            acc[q].x += cur.x; acc[q].y += cur.y; acc[q].z += cur.z; acc[q].w += cur.w;
        }
        if (tid < DHh) {
            float* pz = CZ + ((size_t)bh * NCc + c) * DHh + tid;
            float cur = *pz;
            *pz = accz;
            accz += cur;
        }
    }
}

// ---------------------------------------------------------------------------
// per-chunk output (fp32 compute, spill-free), bf16 output
//   X1=Q, X2=K->V, X3=S_prev->A
// ---------------------------------------------------------------------------
__global__ __launch_bounds__(256)
void chunk_out2(const float* __restrict__ Qp, const unsigned short* __restrict__ Kb,
                const unsigned short* __restrict__ Vb, const float* __restrict__ CS,
                const float* __restrict__ CZ, unsigned short* __restrict__ Ob) {
    const int blk = blockIdx.x;
    const int c  = blk & (NCc - 1);
    const int bh = blk >> 5;
    const int b  = bh >> 4;
    const int h  = bh & 15;
    const int tid = threadIdx.x;
    const int s0 = c * Cc;

    __shared__ __align__(16) float X1[Cc][DHh + 4];
    __shared__ __align__(16) float X2[Cc][DHh + 4];
    __shared__ __align__(16) float X3[Cc][DHh + 4];
    __shared__ float zs[DHh];
    __shared__ float denp[Cc][4];

    const size_t rowbase = ((size_t)b * Ss + s0) * Dd + (size_t)h * DHh;
    const float* csbase = CS + ((size_t)bh * NCc + c) * (DHh * DHh);

    // load Q (fp32) and S_prev (fp32)
#pragma unroll
    for (int it = 0; it < 4; ++it) {
        int idx = tid + it * 256;            // float4 units
        int r = idx >> 4, c4 = (idx & 15) * 4;
        float4 q4 = *reinterpret_cast<const float4*>(Qp + rowbase + (size_t)r * Dd + c4);
        float4 s4 = *reinterpret_cast<const float4*>(csbase + (size_t)idx * 4);
        X1[r][c4 + 0] = q4.x; X1[r][c4 + 1] = q4.y; X1[r][c4 + 2] = q4.z; X1[r][c4 + 3] = q4.w;
        X3[r][c4 + 0] = s4.x; X3[r][c4 + 1] = s4.y; X3[r][c4 + 2] = s4.z; X3[r][c4 + 3] = s4.w;
    }
    // load K (bf16)
#pragma unroll
    for (int it = 0; it < 2; ++it) {
        int idx = tid + it * 256;
        int r = idx >> 3, c8 = (idx & 7) * 8;
        u16x8 kv = *reinterpret_cast<const u16x8*>(Kb + rowbase + (size_t)r * Dd + c8);
#pragma unroll
        for (int q = 0; q < 8; ++q) X2[r][c8 + q] = bf2f(kv[q]);
    }
    if (tid < DHh) zs[tid] = CZ[((size_t)bh * NCc + c) * DHh + tid];
    __syncthreads();

    const int i  = tid >> 2;
    const int tx = tid & 3;
    const int j0 = tx * 16;        // A columns owned
    const int d0 = tx * 16;        // output d-columns owned

    // phase A: scores A[i][j0..j0+15], causal mask, rowsum
    float areg[16];
    float rowpart = 0.f;
#pragma unroll 1
    for (int jj = 0; jj < 16; ++jj) {
        int j = j0 + jj;
        float s = 0.f;
#pragma unroll 4
        for (int e4 = 0; e4 < 16; ++e4) {
            float4 q4 = *reinterpret_cast<const float4*>(&X1[i][e4 * 4]);
            float4 k4 = *reinterpret_cast<const float4*>(&X2[j][e4 * 4]);
            s = fmaf(q4.x, k4.x, fmaf(q4.y, k4.y, fmaf(q4.z, k4.z, fmaf(q4.w, k4.w, s))));
        }
        s = (j <= i) ? s : 0.f;
        areg[jj] = s;
        rowpart += s;
    }

    // phase inter: acc += Q[i][e] * S[e][d0..d0+15]; deni = Q[i].z
    float acc[16];
#pragma unroll
    for (int dd = 0; dd < 16; ++dd) acc[dd] = 0.f;
    float deni = 0.f;
#pragma unroll 4
    for (int e = 0; e < DHh; ++e) {
        float q = X1[i][e];
        deni = fmaf(q, zs[e], deni);
#pragma unroll
        for (int q4 = 0; q4 < 4; ++q4) {
            float4 s4 = *reinterpret_cast<const float4*>(&X3[e][d0 + q4 * 4]);
            acc[q4 * 4 + 0] = fmaf(q, s4.x, acc[q4 * 4 + 0]);
            acc[q4 * 4 + 1] = fmaf(q, s4.y, acc[q4 * 4 + 1]);
            acc[q4 * 4 + 2] = fmaf(q, s4.z, acc[q4 * 4 + 2]);
            acc[q4 * 4 + 3] = fmaf(q, s4.w, acc[q4 * 4 + 3]);
        }
    }
    __syncthreads();   // S and K fully consumed

    // A -> X3, rowsum -> denp, V -> X2
#pragma unroll
    for (int jj = 0; jj < 16; ++jj) X3[i][j0 + jj] = areg[jj];
    denp[i][tx] = rowpart;
#pragma unroll
    for (int it = 0; it < 2; ++it) {
        int idx = tid + it * 256;
        int r = idx >> 3, c8 = (idx & 7) * 8;
        u16x8 vv = *reinterpret_cast<const u16x8*>(Vb + rowbase + (size_t)r * Dd + c8);
#pragma unroll
        for (int q = 0; q < 8; ++q) X2[r][c8 + q] = bf2f(vv[q]);
    }
    __syncthreads();

    // phase intra: acc += A[i][j] * V[j][d0..d0+15]
#pragma unroll 4
    for (int j = 0; j < Cc; ++j) {
        float a = X3[i][j];
#pragma unroll
        for (int q4 = 0; q4 < 4; ++q4) {
            float4 v4 = *reinterpret_cast<const float4*>(&X2[j][d0 + q4 * 4]);
            acc[q4 * 4 + 0] = fmaf(a, v4.x, acc[q4 * 4 + 0]);
            acc[q4 * 4 + 1] = fmaf(a, v4.y, acc[q4 * 4 + 1]);
            acc[q4 * 4 + 2] = fmaf(a, v4.z, acc[q4 * 4 + 2]);
            acc[q4 * 4 + 3] = fmaf(a, v4.w, acc[q4 * 4 + 3]);
        }
    }

    const float den = deni + denp[i][0] + denp[i][1] + denp[i][2] + denp[i][3] + EPSf;
    const float inv = 1.0f / den;
    u16x8 o0, o1;
#pragma unroll
    for (int q = 0; q < 8; ++q) {
        o0[q] = f2bf(acc[q] * inv);
        o1[q] = f2bf(acc[8 + q] * inv);
    }
    unsigned short* orow = Ob + rowbase + (size_t)i * Dd + d0;
    *reinterpret_cast<u16x8*>(orow)     = o0;
    *reinterpret_cast<u16x8*>(orow + 8) = o1;
}

// ---------------------------------------------------------------------------
extern "C" void kernel_launch(void* const* d_in, const int* in_sizes, int n_in,
                              void* d_out, int out_size, void* d_ws, size_t ws_size,
                              hipStream_t stream) {
    const float* x  = (const float*)d_in[0];
    const float* Wq = (const float*)d_in[1];
    const float* Wk = (const float*)d_in[2];
    const float* Wv = (const float*)d_in[3];
    const float* Wo = (const float*)d_in[4];

    const size_t NMD = (size_t)Mm * Dd;       // 8388608
    const size_t NW  = (size_t)Dd * Dd;       // 1048576
    unsigned short* xb  = (unsigned short*)d_ws;           // 16 MB
    unsigned short* WT  = xb + NMD;                        // 8 MB (4 weights)
    unsigned short* Kb  = WT + 4 * NW;                     // 16 MB
    unsigned short* Vb  = Kb + NMD;                        // 16 MB
    unsigned short* Obf = Vb + NMD;                        // 16 MB
    float* CS = (float*)(Obf + NMD);                       // 32 MB
    float* CZ = CS + (size_t)Bb * Hh * NCc * DHh * DHh;    // 0.5 MB
    float* Qb = (float*)d_out;   // Q (fp32) lives in d_out; consumed before final GEMM

    // casts / transposes
    cast_bf16<<<(int)(NMD / 8 + 255) / 256, 256, 0, stream>>>(x, xb, (int)(NMD / 8));
    transpose_cast_w<<<dim3(16, 16, 4), 256, 0, stream>>>(Wq, Wk, Wv, Wo, WT);

    dim3 gg(Dd / 128, Mm / 128);   // (8, 64)
    // projections: Q fp32+phi -> d_out, K bf16+phi, V bf16
    gemm_bf16mfma<1><<<gg, 256, 0, stream>>>(xb, WT + 0 * NW, Qb, nullptr);
    gemm_bf16mfma<3><<<gg, 256, 0, stream>>>(xb, WT + 1 * NW, nullptr, Kb);
    gemm_bf16mfma<2><<<gg, 256, 0, stream>>>(xb, WT + 2 * NW, nullptr, Vb);

    // chunked linear attention
    chunk_sums<<<Bb * Hh * NCc, 256, 0, stream>>>(Kb, Vb, CS, CZ);
    chunk_scan<<<Bb * Hh, 256, 0, stream>>>(CS, CZ);
    chunk_out2<<<Bb * Hh * NCc, 256, 0, stream>>>(Qb, Kb, Vb, CS, CZ, Obf);

    // output projection -> d_out (fp32)
    gemm_bf16mfma<0><<<gg, 256, 0, stream>>>(Obf, WT + 3 * NW, (float*)d_out, nullptr);
}

// Round 3
// 176.232 us; speedup vs baseline: 10.9530x; 1.6239x over previous
//
#include <hip/hip_runtime.h>
#include <hip/hip_bf16.h>
#include <math.h>

// Problem constants
constexpr int Bb  = 4;
constexpr int SEQ = 2048;
constexpr int Dd  = 1024;
constexpr int Hh  = 16;
constexpr int DHh = 64;
constexpr int Cc  = 64;            // chunk length
constexpr int NCc = SEQ / Cc;      // 32 chunks
constexpr int Mm  = Bb * SEQ;      // 8192 rows
constexpr float EPSf = 1e-6f;

typedef __attribute__((ext_vector_type(8))) short bf16x8;
typedef __attribute__((ext_vector_type(4))) float f32x4;
typedef __attribute__((ext_vector_type(8))) unsigned short u16x8;

__device__ __forceinline__ float bf2f(unsigned short u) {
    return __uint_as_float((unsigned)u << 16);
}
__device__ __forceinline__ unsigned short f2bf(float f) {
    unsigned u = __float_as_uint(f);
    unsigned r = u + 0x7fff + ((u >> 16) & 1);   // RNE
    return (unsigned short)(r >> 16);
}
// XOR swizzle for transposed LDS tiles: permutes cols within a row, keyed by row>>3.
// Write conflicts <=2-way, b128 fragment reads <=2-way (bank math in journal).
__device__ __forceinline__ int swz(int row, int col) {
    return col ^ (((row >> 3) & 7) << 3);
}

// ---------------------------------------------------------------------------
// cast fp32 -> bf16, 8 elems/thread
// ---------------------------------------------------------------------------
__global__ __launch_bounds__(256)
void cast_bf16(const float* __restrict__ in, unsigned short* __restrict__ out, int n8) {
    int i = blockIdx.x * 256 + threadIdx.x;
    if (i >= n8) return;
    const float4* p = reinterpret_cast<const float4*>(in) + (size_t)i * 2;
    float4 a = p[0], b = p[1];
    u16x8 o;
    o[0] = f2bf(a.x); o[1] = f2bf(a.y); o[2] = f2bf(a.z); o[3] = f2bf(a.w);
    o[4] = f2bf(b.x); o[5] = f2bf(b.y); o[6] = f2bf(b.z); o[7] = f2bf(b.w);
    *(reinterpret_cast<u16x8*>(out) + i) = o;
}

// ---------------------------------------------------------------------------
// W [K][N] fp32 -> WT bf16 [N][K]; 4 weights selected by blockIdx.z
// ---------------------------------------------------------------------------
__global__ __launch_bounds__(256)
void transpose_cast_w(const float* __restrict__ W0, const float* __restrict__ W1,
                      const float* __restrict__ W2, const float* __restrict__ W3,
                      unsigned short* __restrict__ WT) {
    const float* W = (blockIdx.z == 0) ? W0 : (blockIdx.z == 1) ? W1
                     : (blockIdx.z == 2) ? W2 : W3;
    unsigned short* T = WT + (size_t)blockIdx.z * Dd * Dd;
    __shared__ float t[64][65];
    const int r0 = blockIdx.y * 64, c0 = blockIdx.x * 64;
    const int tid = threadIdx.x;
    const int lr = tid >> 4, lc4 = (tid & 15) * 4;
#pragma unroll
    for (int it = 0; it < 4; ++it) {
        int row = lr + it * 16;
        float4 v = *reinterpret_cast<const float4*>(W + (size_t)(r0 + row) * Dd + c0 + lc4);
        t[row][lc4 + 0] = v.x; t[row][lc4 + 1] = v.y;
        t[row][lc4 + 2] = v.z; t[row][lc4 + 3] = v.w;
    }
    __syncthreads();
#pragma unroll
    for (int it = 0; it < 4; ++it) {
        int col = lr + it * 16;     // tile col -> T row
        ushort4 o;
        o.x = f2bf(t[lc4 + 0][col]); o.y = f2bf(t[lc4 + 1][col]);
        o.z = f2bf(t[lc4 + 2][col]); o.w = f2bf(t[lc4 + 3][col]);
        *reinterpret_cast<ushort4*>(T + (size_t)(c0 + col) * Dd + r0 + lc4) = o;
    }
}

// ---------------------------------------------------------------------------
// bf16 MFMA GEMM (m97 structure): out[M,N] = A[M,K] @ BT[N,K]^T
// 128x128 tile, BK=32, 4 waves (2x2), 4x4 16x16x32 fragments per wave.
// MODE: bit0 = apply phi (elu+1), bit1 = bf16 output (else fp32)
// ---------------------------------------------------------------------------
template<int MODE>
__global__ __launch_bounds__(256)
void gemm_bf16mfma(const unsigned short* __restrict__ A, const unsigned short* __restrict__ BT,
                   float* __restrict__ outF, unsigned short* __restrict__ outB) {
    constexpr int Kd = 1024, Nn = 1024;
    __shared__ __align__(16) unsigned short As[128 * 32];
    __shared__ __align__(16) unsigned short Bs[128 * 32];
    const int tid  = threadIdx.x;
    const int lane = tid & 63;
    const int row0 = blockIdx.y * 128;
    const int col0 = blockIdx.x * 128;
    const int wr = ((tid >> 6) >> 1) * 64;   // wave row offset
    const int wc = ((tid >> 6) & 1) * 64;    // wave col offset
    const int fr = lane & 15;
    const int fk = (lane >> 4) * 8;

    f32x4 acc[4][4];
#pragma unroll
    for (int mf = 0; mf < 4; ++mf)
#pragma unroll
        for (int nf = 0; nf < 4; ++nf) acc[mf][nf] = (f32x4){0.f, 0.f, 0.f, 0.f};

    for (int kt = 0; kt < Kd; kt += 32) {
        // stage: 512 16B segments per matrix, 2 per thread
#pragma unroll
        for (int s = 0; s < 2; ++s) {
            int seg = tid + s * 256;
            int r = seg >> 2, c8 = (seg & 3) * 8;
            __builtin_amdgcn_global_load_lds(
                (const __attribute__((address_space(1))) void*)(A + (size_t)(row0 + r) * Kd + kt + c8),
                (__attribute__((address_space(3))) void*)(As + seg * 8), 16, 0, 0);
            __builtin_amdgcn_global_load_lds(
                (const __attribute__((address_space(1))) void*)(BT + (size_t)(col0 + r) * Kd + kt + c8),
                (__attribute__((address_space(3))) void*)(Bs + seg * 8), 16, 0, 0);
        }
        __syncthreads();
        bf16x8 af[4], bfv[4];
#pragma unroll
        for (int mf = 0; mf < 4; ++mf)
            af[mf] = *reinterpret_cast<const bf16x8*>(As + (wr + mf * 16 + fr) * 32 + fk);
#pragma unroll
        for (int nf = 0; nf < 4; ++nf)
            bfv[nf] = *reinterpret_cast<const bf16x8*>(Bs + (wc + nf * 16 + fr) * 32 + fk);
#pragma unroll
        for (int mf = 0; mf < 4; ++mf)
#pragma unroll
            for (int nf = 0; nf < 4; ++nf)
                acc[mf][nf] = __builtin_amdgcn_mfma_f32_16x16x32_bf16(af[mf], bfv[nf], acc[mf][nf], 0, 0, 0);
        __syncthreads();
    }

    // epilogue: D[row=(lane>>4)*4+r][col=lane&15] per fragment
#pragma unroll
    for (int mf = 0; mf < 4; ++mf) {
#pragma unroll
        for (int nf = 0; nf < 4; ++nf) {
#pragma unroll
            for (int r = 0; r < 4; ++r) {
                int orow = row0 + wr + mf * 16 + (lane >> 4) * 4 + r;
                int ocol = col0 + wc + nf * 16 + fr;
                float v = acc[mf][nf][r];
                if (MODE & 1) v = (v > 0.f) ? (v + 1.f) : __expf(v);
                if (MODE & 2) outB[(size_t)orow * Nn + ocol] = f2bf(v);
                else          outF[(size_t)orow * Nn + ocol] = v;
            }
        }
    }
}

// ---------------------------------------------------------------------------
// chunk_sums (MFMA): CS'[e][d] = sum_j V[j][e]*K[j][d]  (bf16 out)
//                    CZ[d]     = sum_j K[j][d]          (fp32)
// A = V^T (swizzled LDS), B^T = K^T (swizzled LDS). grid = B*H*NC, 256 thr.
// ---------------------------------------------------------------------------
__global__ __launch_bounds__(256)
void chunk_sums_mfma(const unsigned short* __restrict__ Kb, const unsigned short* __restrict__ Vb,
                     unsigned short* __restrict__ CSb, float* __restrict__ CZ) {
    const int blk = blockIdx.x;
    const int c  = blk & (NCc - 1);
    const int bh = blk >> 5;
    const int b  = bh >> 4;
    const int h  = bh & 15;
    const int tid  = threadIdx.x;
    const int wave = tid >> 6, lane = tid & 63;
    const int lo = lane & 15, hi = lane >> 4;
    const int wr = (wave >> 1) * 32, wc = (wave & 1) * 32;

    __shared__ __align__(16) unsigned short Kt[64][72];
    __shared__ __align__(16) unsigned short Vt[64][72];

    const size_t rowbase = ((size_t)b * SEQ + c * Cc) * Dd + (size_t)h * DHh;

#pragma unroll
    for (int it = 0; it < 2; ++it) {
        int idx = tid + it * 256;
        int r = idx >> 3, c8 = (idx & 7) * 8;
        u16x8 kv = *reinterpret_cast<const u16x8*>(Kb + rowbase + (size_t)r * Dd + c8);
        u16x8 vv = *reinterpret_cast<const u16x8*>(Vb + rowbase + (size_t)r * Dd + c8);
#pragma unroll
        for (int q = 0; q < 8; ++q) {
            int d = c8 + q;
            int sc = swz(d, r);
            Kt[d][sc] = kv[q];
            Vt[d][sc] = vv[q];
        }
    }
    __syncthreads();

    f32x4 acc[2][2];
#pragma unroll
    for (int mf = 0; mf < 2; ++mf)
#pragma unroll
        for (int nf = 0; nf < 2; ++nf) acc[mf][nf] = (f32x4){0.f, 0.f, 0.f, 0.f};

#pragma unroll
    for (int kb = 0; kb < 2; ++kb) {
        const int ko = kb * 32 + hi * 8;
        bf16x8 av[2], bk[2];
#pragma unroll
        for (int mf = 0; mf < 2; ++mf) {
            int row = wr + mf * 16 + lo;
            av[mf] = *reinterpret_cast<const bf16x8*>(&Vt[row][swz(row, ko)]);
        }
#pragma unroll
        for (int nf = 0; nf < 2; ++nf) {
            int row = wc + nf * 16 + lo;
            bk[nf] = *reinterpret_cast<const bf16x8*>(&Kt[row][swz(row, ko)]);
        }
#pragma unroll
        for (int mf = 0; mf < 2; ++mf)
#pragma unroll
            for (int nf = 0; nf < 2; ++nf)
                acc[mf][nf] = __builtin_amdgcn_mfma_f32_16x16x32_bf16(av[mf], bk[nf], acc[mf][nf], 0, 0, 0);
    }

    // CZ: row-sum of Kt (swizzle is a within-row permutation, sum invariant)
    if (tid < DHh) {
        float s = 0.f;
#pragma unroll
        for (int e8 = 0; e8 < 8; ++e8) {
            u16x8 k8 = *reinterpret_cast<const u16x8*>(&Kt[tid][e8 * 8]);
#pragma unroll
            for (int q = 0; q < 8; ++q) s += bf2f(k8[q]);
        }
        CZ[((size_t)bh * NCc + c) * DHh + tid] = s;
    }

    unsigned short* csb = CSb + ((size_t)bh * NCc + c) * (DHh * DHh);
#pragma unroll
    for (int mf = 0; mf < 2; ++mf)
#pragma unroll
        for (int nf = 0; nf < 2; ++nf)
#pragma unroll
            for (int r = 0; r < 4; ++r) {
                int e = wr + mf * 16 + hi * 4 + r;
                int d = wc + nf * 16 + lo;
                csb[e * DHh + d] = f2bf(acc[mf][nf][r]);
            }
}

// ---------------------------------------------------------------------------
// exclusive prefix scan over chunks (CS bf16 in-place, CZ fp32 in-place)
// grid = B*H*8; each block owns one 512-element position-slice of one bh.
// ---------------------------------------------------------------------------
__global__ __launch_bounds__(256)
void chunk_scan2(unsigned short* __restrict__ CSb, float* __restrict__ CZ) {
    const int bh = blockIdx.x >> 3;
    const int sl = blockIdx.x & 7;
    const int tid = threadIdx.x;
    const int pos = sl * 512 + tid * 2;
    float a0 = 0.f, a1 = 0.f, accz = 0.f;

    for (int c = 0; c < NCc; ++c) {
        unsigned int* p = reinterpret_cast<unsigned int*>(
            CSb + ((size_t)bh * NCc + c) * (DHh * DHh) + pos);
        unsigned int cur = *p;
        *p = (unsigned)f2bf(a0) | ((unsigned)f2bf(a1) << 16);
        a0 += bf2f((unsigned short)(cur & 0xffff));
        a1 += bf2f((unsigned short)(cur >> 16));
        if (sl == 0 && tid < DHh) {
            float* pz = CZ + ((size_t)bh * NCc + c) * DHh + tid;
            float z = *pz; *pz = accz; accz += z;
        }
    }
}

// ---------------------------------------------------------------------------
// chunk_out (MFMA): O = (mask(QK^T)@V + Q@S_prev) / (q.z_prev + rowsum + eps)
// LDS: Qs,KP,Ss row-major padded; Vt transposed+swizzled; KP reused for P.
// grid = B*H*NC, 256 thr (4 waves, 2x2 over the 64x64 output).
// ---------------------------------------------------------------------------
__global__ __launch_bounds__(256)
void chunk_out_mfma(const unsigned short* __restrict__ Qb, const unsigned short* __restrict__ Kb,
                    const unsigned short* __restrict__ Vb, const unsigned short* __restrict__ CSb,
                    const float* __restrict__ CZ, unsigned short* __restrict__ Ob) {
    const int blk = blockIdx.x;
    const int c  = blk & (NCc - 1);
    const int bh = blk >> 5;
    const int b  = bh >> 4;
    const int h  = bh & 15;
    const int tid  = threadIdx.x;
    const int wave = tid >> 6, lane = tid & 63;
    const int lo = lane & 15, hi = lane >> 4;
    const int wr = (wave >> 1) * 32, wc = (wave & 1) * 32;

    __shared__ __align__(16) unsigned short Qs[64][72];
    __shared__ __align__(16) unsigned short KP[64][72];   // K, then P
    __shared__ __align__(16) unsigned short Ss[64][72];   // S_prev' (CS scanned)
    __shared__ __align__(16) unsigned short Vt[64][72];   // V transposed, swizzled
    __shared__ float zsL[DHh];
    __shared__ float rowp[64][2];
    __shared__ float denL[64];

    const size_t rowbase = ((size_t)b * SEQ + c * Cc) * Dd + (size_t)h * DHh;
    const unsigned short* csb = CSb + ((size_t)bh * NCc + c) * (DHh * DHh);

    // ---- stage ----
#pragma unroll
    for (int it = 0; it < 2; ++it) {
        int idx = tid + it * 256;
        int r = idx >> 3, c8 = (idx & 7) * 8;
        u16x8 qv = *reinterpret_cast<const u16x8*>(Qb + rowbase + (size_t)r * Dd + c8);
        u16x8 kv = *reinterpret_cast<const u16x8*>(Kb + rowbase + (size_t)r * Dd + c8);
        u16x8 vv = *reinterpret_cast<const u16x8*>(Vb + rowbase + (size_t)r * Dd + c8);
        u16x8 sv = *reinterpret_cast<const u16x8*>(csb + idx * 8);
        *reinterpret_cast<u16x8*>(&Qs[r][c8]) = qv;
        *reinterpret_cast<u16x8*>(&KP[r][c8]) = kv;
        *reinterpret_cast<u16x8*>(&Ss[r][c8]) = sv;
#pragma unroll
        for (int q = 0; q < 8; ++q) {
            int d = c8 + q;
            Vt[d][swz(d, r)] = vv[q];
        }
    }
    if (tid < DHh) zsL[tid] = CZ[((size_t)bh * NCc + c) * DHh + tid];
    __syncthreads();

    // ---- scores = Q K^T ; inter = Q S_prev ----
    f32x4 accs[2][2], accO[2][2];
#pragma unroll
    for (int mf = 0; mf < 2; ++mf)
#pragma unroll
        for (int nf = 0; nf < 2; ++nf) {
            accs[mf][nf] = (f32x4){0.f, 0.f, 0.f, 0.f};
            accO[mf][nf] = (f32x4){0.f, 0.f, 0.f, 0.f};
        }

#pragma unroll
    for (int kb = 0; kb < 2; ++kb) {
        const int ko = kb * 32 + hi * 8;
        bf16x8 aq[2], bk[2], bs[2];
#pragma unroll
        for (int mf = 0; mf < 2; ++mf)
            aq[mf] = *reinterpret_cast<const bf16x8*>(&Qs[wr + mf * 16 + lo][ko]);
#pragma unroll
        for (int nf = 0; nf < 2; ++nf) {
            bk[nf] = *reinterpret_cast<const bf16x8*>(&KP[wc + nf * 16 + lo][ko]);
            bs[nf] = *reinterpret_cast<const bf16x8*>(&Ss[wc + nf * 16 + lo][ko]);
        }
#pragma unroll
        for (int mf = 0; mf < 2; ++mf)
#pragma unroll
            for (int nf = 0; nf < 2; ++nf) {
                accs[mf][nf] = __builtin_amdgcn_mfma_f32_16x16x32_bf16(aq[mf], bk[nf], accs[mf][nf], 0, 0, 0);
                accO[mf][nf] = __builtin_amdgcn_mfma_f32_16x16x32_bf16(aq[mf], bs[nf], accO[mf][nf], 0, 0, 0);
            }
    }

    // ---- mask + rowsum (shfl over the 16-lane lo-group) ----
#pragma unroll
    for (int mf = 0; mf < 2; ++mf)
#pragma unroll
        for (int r = 0; r < 4; ++r) {
            int i = wr + mf * 16 + hi * 4 + r;
            float s = 0.f;
#pragma unroll
            for (int nf = 0; nf < 2; ++nf) {
                int j = wc + nf * 16 + lo;
                float v = (j <= i) ? accs[mf][nf][r] : 0.f;
                accs[mf][nf][r] = v;
                s += v;
            }
            s += __shfl_xor(s, 1); s += __shfl_xor(s, 2);
            s += __shfl_xor(s, 4); s += __shfl_xor(s, 8);
            if (lo == 0) rowp[i][wave & 1] = s;
        }
    __syncthreads();   // scores MFMA reads of KP done; rowp visible

    // ---- P (bf16) -> KP buffer; den on 64 threads ----
#pragma unroll
    for (int mf = 0; mf < 2; ++mf)
#pragma unroll
        for (int nf = 0; nf < 2; ++nf)
#pragma unroll
            for (int r = 0; r < 4; ++r)
                KP[wr + mf * 16 + hi * 4 + r][wc + nf * 16 + lo] = f2bf(accs[mf][nf][r]);
    if (tid < 64) {
        float d = 0.f;
#pragma unroll
        for (int e8 = 0; e8 < 8; ++e8) {
            u16x8 q8 = *reinterpret_cast<const u16x8*>(&Qs[tid][e8 * 8]);
#pragma unroll
            for (int q = 0; q < 8; ++q) d += bf2f(q8[q]) * zsL[e8 * 8 + q];
        }
        denL[tid] = d + rowp[tid][0] + rowp[tid][1] + EPSf;
    }
    __syncthreads();

    // ---- intra: accO += P V ----
#pragma unroll
    for (int kb = 0; kb < 2; ++kb) {
        const int ko = kb * 32 + hi * 8;
        bf16x8 ap[2], bv[2];
#pragma unroll
        for (int mf = 0; mf < 2; ++mf)
            ap[mf] = *reinterpret_cast<const bf16x8*>(&KP[wr + mf * 16 + lo][ko]);
#pragma unroll
        for (int nf = 0; nf < 2; ++nf) {
            int row = wc + nf * 16 + lo;
            bv[nf] = *reinterpret_cast<const bf16x8*>(&Vt[row][swz(row, ko)]);
        }
#pragma unroll
        for (int mf = 0; mf < 2; ++mf)
#pragma unroll
            for (int nf = 0; nf < 2; ++nf)
                accO[mf][nf] = __builtin_amdgcn_mfma_f32_16x16x32_bf16(ap[mf], bv[nf], accO[mf][nf], 0, 0, 0);
    }

    // ---- epilogue ----
#pragma unroll
    for (int mf = 0; mf < 2; ++mf)
#pragma unroll
        for (int r = 0; r < 4; ++r) {
            int i = wr + mf * 16 + hi * 4 + r;
            float inv = 1.0f / denL[i];
#pragma unroll
            for (int nf = 0; nf < 2; ++nf) {
                int e = wc + nf * 16 + lo;
                Ob[rowbase + (size_t)i * Dd + e] = f2bf(accO[mf][nf][r] * inv);
            }
        }
}

// ---------------------------------------------------------------------------
extern "C" void kernel_launch(void* const* d_in, const int* in_sizes, int n_in,
                              void* d_out, int out_size, void* d_ws, size_t ws_size,
                              hipStream_t stream) {
    const float* x  = (const float*)d_in[0];
    const float* Wq = (const float*)d_in[1];
    const float* Wk = (const float*)d_in[2];
    const float* Wv = (const float*)d_in[3];
    const float* Wo = (const float*)d_in[4];

    const size_t NMD = (size_t)Mm * Dd;       // 8388608
    const size_t NW  = (size_t)Dd * Dd;       // 1048576
    unsigned short* xb  = (unsigned short*)d_ws;           // 16 MB
    unsigned short* WT  = xb + NMD;                        // 8 MB (4 weights)
    unsigned short* Qb  = WT + 4 * NW;                     // 16 MB
    unsigned short* Kb  = Qb + NMD;                        // 16 MB
    unsigned short* Vb  = Kb + NMD;                        // 16 MB
    unsigned short* Obf = Vb + NMD;                        // 16 MB
    unsigned short* CSb = Obf + NMD;                       // 16 MB (bf16, scanned in-place)
    float* CZ = (float*)(CSb + NMD);                       // 0.5 MB

    // casts / transposes
    cast_bf16<<<(int)(NMD / 8 + 255) / 256, 256, 0, stream>>>(x, xb, (int)(NMD / 8));
    transpose_cast_w<<<dim3(16, 16, 4), 256, 0, stream>>>(Wq, Wk, Wv, Wo, WT);

    dim3 gg(Dd / 128, Mm / 128);   // (8, 64)
    // projections: Q bf16+phi, K bf16+phi, V bf16
    gemm_bf16mfma<3><<<gg, 256, 0, stream>>>(xb, WT + 0 * NW, nullptr, Qb);
    gemm_bf16mfma<3><<<gg, 256, 0, stream>>>(xb, WT + 1 * NW, nullptr, Kb);
    gemm_bf16mfma<2><<<gg, 256, 0, stream>>>(xb, WT + 2 * NW, nullptr, Vb);

    // chunked linear attention (MFMA)
    chunk_sums_mfma<<<Bb * Hh * NCc, 256, 0, stream>>>(Kb, Vb, CSb, CZ);
    chunk_scan2<<<Bb * Hh * 8, 256, 0, stream>>>(CSb, CZ);
    chunk_out_mfma<<<Bb * Hh * NCc, 256, 0, stream>>>(Qb, Kb, Vb, CSb, CZ, Obf);

    // output projection -> d_out (fp32)
    gemm_bf16mfma<0><<<gg, 256, 0, stream>>>(Obf, WT + 3 * NW, (float*)d_out, nullptr);
}

// Round 4
// 160.297 us; speedup vs baseline: 12.0419x; 1.0994x over previous
//
#include <hip/hip_runtime.h>
#include <hip/hip_bf16.h>
#include <math.h>

// Problem constants
constexpr int Bb  = 4;
constexpr int SEQ = 2048;
constexpr int Dd  = 1024;
constexpr int Hh  = 16;
constexpr int DHh = 64;
constexpr int Cc  = 64;            // chunk length
constexpr int NCc = SEQ / Cc;      // 32 chunks
constexpr int Mm  = Bb * SEQ;      // 8192 rows
constexpr float EPSf = 1e-6f;

typedef __attribute__((ext_vector_type(8))) short bf16x8;
typedef __attribute__((ext_vector_type(4))) float f32x4;
typedef __attribute__((ext_vector_type(8))) unsigned short u16x8;

__device__ __forceinline__ float bf2f(unsigned short u) {
    return __uint_as_float((unsigned)u << 16);
}
__device__ __forceinline__ unsigned short f2bf(float f) {
    unsigned u = __float_as_uint(f);
    unsigned r = u + 0x7fff + ((u >> 16) & 1);   // RNE
    return (unsigned short)(r >> 16);
}
// XOR swizzle for transposed LDS tiles: permutes cols within a row, keyed by row>>3.
__device__ __forceinline__ int swz(int row, int col) {
    return col ^ (((row >> 3) & 7) << 3);
}

// ---------------------------------------------------------------------------
// cast fp32 -> bf16, 8 elems/thread
// ---------------------------------------------------------------------------
__global__ __launch_bounds__(256)
void cast_bf16(const float* __restrict__ in, unsigned short* __restrict__ out, int n8) {
    int i = blockIdx.x * 256 + threadIdx.x;
    if (i >= n8) return;
    const float4* p = reinterpret_cast<const float4*>(in) + (size_t)i * 2;
    float4 a = p[0], b = p[1];
    u16x8 o;
    o[0] = f2bf(a.x); o[1] = f2bf(a.y); o[2] = f2bf(a.z); o[3] = f2bf(a.w);
    o[4] = f2bf(b.x); o[5] = f2bf(b.y); o[6] = f2bf(b.z); o[7] = f2bf(b.w);
    *(reinterpret_cast<u16x8*>(out) + i) = o;
}

// ---------------------------------------------------------------------------
// W [K][N] fp32 -> WT bf16 [N][K]; 4 weights selected by blockIdx.z
// ---------------------------------------------------------------------------
__global__ __launch_bounds__(256)
void transpose_cast_w(const float* __restrict__ W0, const float* __restrict__ W1,
                      const float* __restrict__ W2, const float* __restrict__ W3,
                      unsigned short* __restrict__ WT) {
    const float* W = (blockIdx.z == 0) ? W0 : (blockIdx.z == 1) ? W1
                     : (blockIdx.z == 2) ? W2 : W3;
    unsigned short* T = WT + (size_t)blockIdx.z * Dd * Dd;
    __shared__ float t[64][65];
    const int r0 = blockIdx.y * 64, c0 = blockIdx.x * 64;
    const int tid = threadIdx.x;
    const int lr = tid >> 4, lc4 = (tid & 15) * 4;
#pragma unroll
    for (int it = 0; it < 4; ++it) {
        int row = lr + it * 16;
        float4 v = *reinterpret_cast<const float4*>(W + (size_t)(r0 + row) * Dd + c0 + lc4);
        t[row][lc4 + 0] = v.x; t[row][lc4 + 1] = v.y;
        t[row][lc4 + 2] = v.z; t[row][lc4 + 3] = v.w;
    }
    __syncthreads();
#pragma unroll
    for (int it = 0; it < 4; ++it) {
        int col = lr + it * 16;     // tile col -> T row
        ushort4 o;
        o.x = f2bf(t[lc4 + 0][col]); o.y = f2bf(t[lc4 + 1][col]);
        o.z = f2bf(t[lc4 + 2][col]); o.w = f2bf(t[lc4 + 3][col]);
        *reinterpret_cast<ushort4*>(T + (size_t)(c0 + col) * Dd + r0 + lc4) = o;
    }
}

// ---------------------------------------------------------------------------
// bf16 MFMA GEMM, 2-phase double-buffered LDS (T3 minimum recipe):
//   prologue stage(buf0); loop { stage(buf^1,t+1); ds_read+MFMA buf[cur];
//   __syncthreads(); flip; }  -- one barrier+vmcnt(0) per K-step, next tile's
//   global_load_lds in flight under current tile's compute.
// out[M,N] = A[M,K=1024] @ BT[N,K]^T, 128x128 tile, 4 waves (2x2), 4x4 frags.
// QKV=1: N=3072 fused (Wq|Wk|Wv), bf16 out, phi on first two kiloblocks.
// QKV=0: N=1024, fp32 out, no phi.
// Grid: 1D NWG blocks, bijective XCD swizzle (NWG % 8 == 0).
// ---------------------------------------------------------------------------
template<int QKV>
__global__ __launch_bounds__(256)
void gemm_dbuf(const unsigned short* __restrict__ A, const unsigned short* __restrict__ BT,
               float* __restrict__ outF, unsigned short* __restrict__ oQ,
               unsigned short* __restrict__ oK, unsigned short* __restrict__ oV) {
    constexpr int Kd  = 1024;
    constexpr int GX  = QKV ? 24 : 8;      // N / 128
    constexpr int NWG = GX * 64;           // (M/128) * GX
    constexpr int NT  = Kd / 32;           // 32 K-steps

    __shared__ __align__(16) unsigned short As[2][128 * 32];
    __shared__ __align__(16) unsigned short Bs[2][128 * 32];

    // bijective XCD swizzle: consecutive swizzled ids land on one XCD
    const int wg0 = blockIdx.x;
    const int wg  = (wg0 & 7) * (NWG >> 3) + (wg0 >> 3);
    const int bx = wg % GX, by = wg / GX;
    const int row0 = by * 128;
    const int col0 = bx * 128;             // global N coordinate (0..GX*128)

    const int tid  = threadIdx.x;
    const int lane = tid & 63;
    const int wr = ((tid >> 6) >> 1) * 64;
    const int wc = ((tid >> 6) & 1) * 64;
    const int fr = lane & 15;
    const int fk = (lane >> 4) * 8;

    // staging coords: 512 16B segments per matrix, 2 per thread
    const int sr = tid >> 2;               // row 0..63 (x2 via s)
    const int sc8 = (tid & 3) * 8;

    f32x4 acc[4][4];
#pragma unroll
    for (int mf = 0; mf < 4; ++mf)
#pragma unroll
        for (int nf = 0; nf < 4; ++nf) acc[mf][nf] = (f32x4){0.f, 0.f, 0.f, 0.f};

    auto stage = [&](int buf, int kt) {
#pragma unroll
        for (int s = 0; s < 2; ++s) {
            int r = sr + s * 64;
            int seg = tid + s * 256;
            __builtin_amdgcn_global_load_lds(
                (const __attribute__((address_space(1))) void*)(A + (size_t)(row0 + r) * Kd + kt + sc8),
                (__attribute__((address_space(3))) void*)(&As[buf][seg * 8]), 16, 0, 0);
            __builtin_amdgcn_global_load_lds(
                (const __attribute__((address_space(1))) void*)(BT + (size_t)(col0 + r) * Kd + kt + sc8),
                (__attribute__((address_space(3))) void*)(&Bs[buf][seg * 8]), 16, 0, 0);
        }
    };

    stage(0, 0);
    __syncthreads();                       // vmcnt(0) drain + barrier (tile 0 ready)

    int cur = 0;
    for (int t = 0; t < NT; ++t) {
        if (t + 1 < NT) stage(cur ^ 1, (t + 1) * 32);   // issue-early, lands under compute
        bf16x8 af[4], bfv[4];
#pragma unroll
        for (int mf = 0; mf < 4; ++mf)
            af[mf] = *reinterpret_cast<const bf16x8*>(&As[cur][(wr + mf * 16 + fr) * 32 + fk]);
#pragma unroll
        for (int nf = 0; nf < 4; ++nf)
            bfv[nf] = *reinterpret_cast<const bf16x8*>(&Bs[cur][(wc + nf * 16 + fr) * 32 + fk]);
#pragma unroll
        for (int mf = 0; mf < 4; ++mf)
#pragma unroll
            for (int nf = 0; nf < 4; ++nf)
                acc[mf][nf] = __builtin_amdgcn_mfma_f32_16x16x32_bf16(af[mf], bfv[nf], acc[mf][nf], 0, 0, 0);
        __syncthreads();                   // drains stage(t+1) + all ds_reads; flip safe
        cur ^= 1;
    }

    // epilogue: D[row=(lane>>4)*4+r][col=lane&15] per fragment
    if (QKV) {
        const int sel = col0 >> 10;        // 0=Q,1=K,2=V
        unsigned short* ob = (sel == 0) ? oQ : (sel == 1) ? oK : oV;
        const bool phi = (sel < 2);
        const int ncol0 = col0 & 1023;
#pragma unroll
        for (int mf = 0; mf < 4; ++mf)
#pragma unroll
            for (int nf = 0; nf < 4; ++nf)
#pragma unroll
                for (int r = 0; r < 4; ++r) {
                    int orow = row0 + wr + mf * 16 + (lane >> 4) * 4 + r;
                    int ocol = ncol0 + wc + nf * 16 + fr;
                    float v = acc[mf][nf][r];
                    if (phi) v = (v > 0.f) ? (v + 1.f) : __expf(v);
                    ob[(size_t)orow * Dd + ocol] = f2bf(v);
                }
    } else {
#pragma unroll
        for (int mf = 0; mf < 4; ++mf)
#pragma unroll
            for (int nf = 0; nf < 4; ++nf)
#pragma unroll
                for (int r = 0; r < 4; ++r) {
                    int orow = row0 + wr + mf * 16 + (lane >> 4) * 4 + r;
                    int ocol = col0 + wc + nf * 16 + fr;
                    outF[(size_t)orow * Dd + ocol] = acc[mf][nf][r];
                }
    }
}

// ---------------------------------------------------------------------------
// chunk_sums (MFMA): CS'[e][d] = sum_j V[j][e]*K[j][d]  (bf16 out)
//                    CZ[d]     = sum_j K[j][d]          (fp32)
// ---------------------------------------------------------------------------
__global__ __launch_bounds__(256)
void chunk_sums_mfma(const unsigned short* __restrict__ Kb, const unsigned short* __restrict__ Vb,
                     unsigned short* __restrict__ CSb, float* __restrict__ CZ) {
    const int blk = blockIdx.x;
    const int c  = blk & (NCc - 1);
    const int bh = blk >> 5;
    const int b  = bh >> 4;
    const int h  = bh & 15;
    const int tid  = threadIdx.x;
    const int wave = tid >> 6, lane = tid & 63;
    const int lo = lane & 15, hi = lane >> 4;
    const int wr = (wave >> 1) * 32, wc = (wave & 1) * 32;

    __shared__ __align__(16) unsigned short Kt[64][72];
    __shared__ __align__(16) unsigned short Vt[64][72];

    const size_t rowbase = ((size_t)b * SEQ + c * Cc) * Dd + (size_t)h * DHh;

#pragma unroll
    for (int it = 0; it < 2; ++it) {
        int idx = tid + it * 256;
        int r = idx >> 3, c8 = (idx & 7) * 8;
        u16x8 kv = *reinterpret_cast<const u16x8*>(Kb + rowbase + (size_t)r * Dd + c8);
        u16x8 vv = *reinterpret_cast<const u16x8*>(Vb + rowbase + (size_t)r * Dd + c8);
#pragma unroll
        for (int q = 0; q < 8; ++q) {
            int d = c8 + q;
            int sc = swz(d, r);
            Kt[d][sc] = kv[q];
            Vt[d][sc] = vv[q];
        }
    }
    __syncthreads();

    f32x4 acc[2][2];
#pragma unroll
    for (int mf = 0; mf < 2; ++mf)
#pragma unroll
        for (int nf = 0; nf < 2; ++nf) acc[mf][nf] = (f32x4){0.f, 0.f, 0.f, 0.f};

#pragma unroll
    for (int kb = 0; kb < 2; ++kb) {
        const int ko = kb * 32 + hi * 8;
        bf16x8 av[2], bk[2];
#pragma unroll
        for (int mf = 0; mf < 2; ++mf) {
            int row = wr + mf * 16 + lo;
            av[mf] = *reinterpret_cast<const bf16x8*>(&Vt[row][swz(row, ko)]);
        }
#pragma unroll
        for (int nf = 0; nf < 2; ++nf) {
            int row = wc + nf * 16 + lo;
            bk[nf] = *reinterpret_cast<const bf16x8*>(&Kt[row][swz(row, ko)]);
        }
#pragma unroll
        for (int mf = 0; mf < 2; ++mf)
#pragma unroll
            for (int nf = 0; nf < 2; ++nf)
                acc[mf][nf] = __builtin_amdgcn_mfma_f32_16x16x32_bf16(av[mf], bk[nf], acc[mf][nf], 0, 0, 0);
    }

    if (tid < DHh) {
        float s = 0.f;
#pragma unroll
        for (int e8 = 0; e8 < 8; ++e8) {
            u16x8 k8 = *reinterpret_cast<const u16x8*>(&Kt[tid][e8 * 8]);
#pragma unroll
            for (int q = 0; q < 8; ++q) s += bf2f(k8[q]);
        }
        CZ[((size_t)bh * NCc + c) * DHh + tid] = s;
    }

    unsigned short* csb = CSb + ((size_t)bh * NCc + c) * (DHh * DHh);
#pragma unroll
    for (int mf = 0; mf < 2; ++mf)
#pragma unroll
        for (int nf = 0; nf < 2; ++nf)
#pragma unroll
            for (int r = 0; r < 4; ++r) {
                int e = wr + mf * 16 + hi * 4 + r;
                int d = wc + nf * 16 + lo;
                csb[e * DHh + d] = f2bf(acc[mf][nf][r]);
            }
}

// ---------------------------------------------------------------------------
// exclusive prefix scan over chunks (CS bf16 in-place, CZ fp32 in-place)
// ---------------------------------------------------------------------------
__global__ __launch_bounds__(256)
void chunk_scan2(unsigned short* __restrict__ CSb, float* __restrict__ CZ) {
    const int bh = blockIdx.x >> 3;
    const int sl = blockIdx.x & 7;
    const int tid = threadIdx.x;
    const int pos = sl * 512 + tid * 2;
    float a0 = 0.f, a1 = 0.f, accz = 0.f;

    for (int c = 0; c < NCc; ++c) {
        unsigned int* p = reinterpret_cast<unsigned int*>(
            CSb + ((size_t)bh * NCc + c) * (DHh * DHh) + pos);
        unsigned int cur = *p;
        *p = (unsigned)f2bf(a0) | ((unsigned)f2bf(a1) << 16);
        a0 += bf2f((unsigned short)(cur & 0xffff));
        a1 += bf2f((unsigned short)(cur >> 16));
        if (sl == 0 && tid < DHh) {
            float* pz = CZ + ((size_t)bh * NCc + c) * DHh + tid;
            float z = *pz; *pz = accz; accz += z;
        }
    }
}

// ---------------------------------------------------------------------------
// chunk_out (MFMA): O = (mask(QK^T)@V + Q@S_prev) / (q.z_prev + rowsum + eps)
// ---------------------------------------------------------------------------
__global__ __launch_bounds__(256)
void chunk_out_mfma(const unsigned short* __restrict__ Qb, const unsigned short* __restrict__ Kb,
                    const unsigned short* __restrict__ Vb, const unsigned short* __restrict__ CSb,
                    const float* __restrict__ CZ, unsigned short* __restrict__ Ob) {
    const int blk = blockIdx.x;
    const int c  = blk & (NCc - 1);
    const int bh = blk >> 5;
    const int b  = bh >> 4;
    const int h  = bh & 15;
    const int tid  = threadIdx.x;
    const int wave = tid >> 6, lane = tid & 63;
    const int lo = lane & 15, hi = lane >> 4;
    const int wr = (wave >> 1) * 32, wc = (wave & 1) * 32;

    __shared__ __align__(16) unsigned short Qs[64][72];
    __shared__ __align__(16) unsigned short KP[64][72];   // K, then P
    __shared__ __align__(16) unsigned short Ss[64][72];   // S_prev' (CS scanned)
    __shared__ __align__(16) unsigned short Vt[64][72];   // V transposed, swizzled
    __shared__ float zsL[DHh];
    __shared__ float rowp[64][2];
    __shared__ float denL[64];

    const size_t rowbase = ((size_t)b * SEQ + c * Cc) * Dd + (size_t)h * DHh;
    const unsigned short* csb = CSb + ((size_t)bh * NCc + c) * (DHh * DHh);

#pragma unroll
    for (int it = 0; it < 2; ++it) {
        int idx = tid + it * 256;
        int r = idx >> 3, c8 = (idx & 7) * 8;
        u16x8 qv = *reinterpret_cast<const u16x8*>(Qb + rowbase + (size_t)r * Dd + c8);
        u16x8 kv = *reinterpret_cast<const u16x8*>(Kb + rowbase + (size_t)r * Dd + c8);
        u16x8 vv = *reinterpret_cast<const u16x8*>(Vb + rowbase + (size_t)r * Dd + c8);
        u16x8 sv = *reinterpret_cast<const u16x8*>(csb + idx * 8);
        *reinterpret_cast<u16x8*>(&Qs[r][c8]) = qv;
        *reinterpret_cast<u16x8*>(&KP[r][c8]) = kv;
        *reinterpret_cast<u16x8*>(&Ss[r][c8]) = sv;
#pragma unroll
        for (int q = 0; q < 8; ++q) {
            int d = c8 + q;
            Vt[d][swz(d, r)] = vv[q];
        }
    }
    if (tid < DHh) zsL[tid] = CZ[((size_t)bh * NCc + c) * DHh + tid];
    __syncthreads();

    f32x4 accs[2][2], accO[2][2];
#pragma unroll
    for (int mf = 0; mf < 2; ++mf)
#pragma unroll
        for (int nf = 0; nf < 2; ++nf) {
            accs[mf][nf] = (f32x4){0.f, 0.f, 0.f, 0.f};
            accO[mf][nf] = (f32x4){0.f, 0.f, 0.f, 0.f};
        }

#pragma unroll
    for (int kb = 0; kb < 2; ++kb) {
        const int ko = kb * 32 + hi * 8;
        bf16x8 aq[2], bk[2], bs[2];
#pragma unroll
        for (int mf = 0; mf < 2; ++mf)
            aq[mf] = *reinterpret_cast<const bf16x8*>(&Qs[wr + mf * 16 + lo][ko]);
#pragma unroll
        for (int nf = 0; nf < 2; ++nf) {
            bk[nf] = *reinterpret_cast<const bf16x8*>(&KP[wc + nf * 16 + lo][ko]);
            bs[nf] = *reinterpret_cast<const bf16x8*>(&Ss[wc + nf * 16 + lo][ko]);
        }
#pragma unroll
        for (int mf = 0; mf < 2; ++mf)
#pragma unroll
            for (int nf = 0; nf < 2; ++nf) {
                accs[mf][nf] = __builtin_amdgcn_mfma_f32_16x16x32_bf16(aq[mf], bk[nf], accs[mf][nf], 0, 0, 0);
                accO[mf][nf] = __builtin_amdgcn_mfma_f32_16x16x32_bf16(aq[mf], bs[nf], accO[mf][nf], 0, 0, 0);
            }
    }

    // mask + rowsum (shfl over the 16-lane lo-group)
#pragma unroll
    for (int mf = 0; mf < 2; ++mf)
#pragma unroll
        for (int r = 0; r < 4; ++r) {
            int i = wr + mf * 16 + hi * 4 + r;
            float s = 0.f;
#pragma unroll
            for (int nf = 0; nf < 2; ++nf) {
                int j = wc + nf * 16 + lo;
                float v = (j <= i) ? accs[mf][nf][r] : 0.f;
                accs[mf][nf][r] = v;
                s += v;
            }
            s += __shfl_xor(s, 1); s += __shfl_xor(s, 2);
            s += __shfl_xor(s, 4); s += __shfl_xor(s, 8);
            if (lo == 0) rowp[i][wave & 1] = s;
        }
    __syncthreads();

    // P (bf16) -> KP buffer; den on 64 threads
#pragma unroll
    for (int mf = 0; mf < 2; ++mf)
#pragma unroll
        for (int nf = 0; nf < 2; ++nf)
#pragma unroll
            for (int r = 0; r < 4; ++r)
                KP[wr + mf * 16 + hi * 4 + r][wc + nf * 16 + lo] = f2bf(accs[mf][nf][r]);
    if (tid < 64) {
        float d = 0.f;
#pragma unroll
        for (int e8 = 0; e8 < 8; ++e8) {
            u16x8 q8 = *reinterpret_cast<const u16x8*>(&Qs[tid][e8 * 8]);
#pragma unroll
            for (int q = 0; q < 8; ++q) d += bf2f(q8[q]) * zsL[e8 * 8 + q];
        }
        denL[tid] = d + rowp[tid][0] + rowp[tid][1] + EPSf;
    }
    __syncthreads();

    // intra: accO += P V
#pragma unroll
    for (int kb = 0; kb < 2; ++kb) {
        const int ko = kb * 32 + hi * 8;
        bf16x8 ap[2], bv[2];
#pragma unroll
        for (int mf = 0; mf < 2; ++mf)
            ap[mf] = *reinterpret_cast<const bf16x8*>(&KP[wr + mf * 16 + lo][ko]);
#pragma unroll
        for (int nf = 0; nf < 2; ++nf) {
            int row = wc + nf * 16 + lo;
            bv[nf] = *reinterpret_cast<const bf16x8*>(&Vt[row][swz(row, ko)]);
        }
#pragma unroll
        for (int mf = 0; mf < 2; ++mf)
#pragma unroll
            for (int nf = 0; nf < 2; ++nf)
                accO[mf][nf] = __builtin_amdgcn_mfma_f32_16x16x32_bf16(ap[mf], bv[nf], accO[mf][nf], 0, 0, 0);
    }

    // epilogue
#pragma unroll
    for (int mf = 0; mf < 2; ++mf)
#pragma unroll
        for (int r = 0; r < 4; ++r) {
            int i = wr + mf * 16 + hi * 4 + r;
            float inv = 1.0f / denL[i];
#pragma unroll
            for (int nf = 0; nf < 2; ++nf) {
                int e = wc + nf * 16 + lo;
                Ob[rowbase + (size_t)i * Dd + e] = f2bf(accO[mf][nf][r] * inv);
            }
        }
}

// ---------------------------------------------------------------------------
extern "C" void kernel_launch(void* const* d_in, const int* in_sizes, int n_in,
                              void* d_out, int out_size, void* d_ws, size_t ws_size,
                              hipStream_t stream) {
    const float* x  = (const float*)d_in[0];
    const float* Wq = (const float*)d_in[1];
    const float* Wk = (const float*)d_in[2];
    const float* Wv = (const float*)d_in[3];
    const float* Wo = (const float*)d_in[4];

    const size_t NMD = (size_t)Mm * Dd;       // 8388608
    const size_t NW  = (size_t)Dd * Dd;       // 1048576
    unsigned short* xb  = (unsigned short*)d_ws;           // 16 MB
    unsigned short* WT  = xb + NMD;                        // 8 MB (Wq^T|Wk^T|Wv^T|Wo^T)
    unsigned short* Qb  = WT + 4 * NW;                     // 16 MB
    unsigned short* Kb  = Qb + NMD;                        // 16 MB
    unsigned short* Vb  = Kb + NMD;                        // 16 MB
    unsigned short* Obf = Vb + NMD;                        // 16 MB
    unsigned short* CSb = Obf + NMD;                       // 16.8 MB (bf16, scanned in-place)
    float* CZ = (float*)(CSb + (size_t)Bb * Hh * NCc * DHh * DHh); // 0.5 MB

    // casts / transposes
    cast_bf16<<<(int)(NMD / 8 + 255) / 256, 256, 0, stream>>>(x, xb, (int)(NMD / 8));
    transpose_cast_w<<<dim3(16, 16, 4), 256, 0, stream>>>(Wq, Wk, Wv, Wo, WT);

    // fused QKV projection: N=3072 over contiguous (Wq^T|Wk^T|Wv^T); phi on Q,K
    gemm_dbuf<1><<<24 * 64, 256, 0, stream>>>(xb, WT, nullptr, Qb, Kb, Vb);

    // chunked linear attention (MFMA)
    chunk_sums_mfma<<<Bb * Hh * NCc, 256, 0, stream>>>(Kb, Vb, CSb, CZ);
    chunk_scan2<<<Bb * Hh * 8, 256, 0, stream>>>(CSb, CZ);
    chunk_out_mfma<<<Bb * Hh * NCc, 256, 0, stream>>>(Qb, Kb, Vb, CSb, CZ, Obf);

    // output projection -> d_out (fp32)
    gemm_dbuf<0><<<8 * 64, 256, 0, stream>>>(Obf, WT + 3 * NW, (float*)d_out, nullptr, nullptr, nullptr);
}

// Round 5
// 143.641 us; speedup vs baseline: 13.4382x; 1.1160x over previous
//
#include <hip/hip_runtime.h>
#include <hip/hip_bf16.h>
#include <math.h>

// Problem constants
constexpr int Bb  = 4;
constexpr int SEQ = 2048;
constexpr int Dd  = 1024;
constexpr int Hh  = 16;
constexpr int DHh = 64;
constexpr int Cc  = 64;            // chunk length
constexpr int NCc = SEQ / Cc;      // 32 chunks
constexpr int Mm  = Bb * SEQ;      // 8192 rows
constexpr float EPSf = 1e-6f;

typedef __attribute__((ext_vector_type(8))) short bf16x8;
typedef __attribute__((ext_vector_type(4))) float f32x4;
typedef __attribute__((ext_vector_type(8))) unsigned short u16x8;

__device__ __forceinline__ float bf2f(unsigned short u) {
    return __uint_as_float((unsigned)u << 16);
}
__device__ __forceinline__ unsigned short f2bf(float f) {
    unsigned u = __float_as_uint(f);
    unsigned r = u + 0x7fff + ((u >> 16) & 1);   // RNE
    return (unsigned short)(r >> 16);
}
// XOR swizzle for transposed LDS tiles (chunk kernels)
__device__ __forceinline__ int swz(int row, int col) {
    return col ^ (((row >> 3) & 7) << 3);
}

// ---------------------------------------------------------------------------
// cast fp32 -> bf16, 8 elems/thread
// ---------------------------------------------------------------------------
__global__ __launch_bounds__(256)
void cast_bf16(const float* __restrict__ in, unsigned short* __restrict__ out, int n8) {
    int i = blockIdx.x * 256 + threadIdx.x;
    if (i >= n8) return;
    const float4* p = reinterpret_cast<const float4*>(in) + (size_t)i * 2;
    float4 a = p[0], b = p[1];
    u16x8 o;
    o[0] = f2bf(a.x); o[1] = f2bf(a.y); o[2] = f2bf(a.z); o[3] = f2bf(a.w);
    o[4] = f2bf(b.x); o[5] = f2bf(b.y); o[6] = f2bf(b.z); o[7] = f2bf(b.w);
    *(reinterpret_cast<u16x8*>(out) + i) = o;
}

// ---------------------------------------------------------------------------
// W [K][N] fp32 -> WT bf16 [N][K]; 4 weights selected by blockIdx.z
// ---------------------------------------------------------------------------
__global__ __launch_bounds__(256)
void transpose_cast_w(const float* __restrict__ W0, const float* __restrict__ W1,
                      const float* __restrict__ W2, const float* __restrict__ W3,
                      unsigned short* __restrict__ WT) {
    const float* W = (blockIdx.z == 0) ? W0 : (blockIdx.z == 1) ? W1
                     : (blockIdx.z == 2) ? W2 : W3;
    unsigned short* T = WT + (size_t)blockIdx.z * Dd * Dd;
    __shared__ float t[64][65];
    const int r0 = blockIdx.y * 64, c0 = blockIdx.x * 64;
    const int tid = threadIdx.x;
    const int lr = tid >> 4, lc4 = (tid & 15) * 4;
#pragma unroll
    for (int it = 0; it < 4; ++it) {
        int row = lr + it * 16;
        float4 v = *reinterpret_cast<const float4*>(W + (size_t)(r0 + row) * Dd + c0 + lc4);
        t[row][lc4 + 0] = v.x; t[row][lc4 + 1] = v.y;
        t[row][lc4 + 2] = v.z; t[row][lc4 + 3] = v.w;
    }
    __syncthreads();
#pragma unroll
    for (int it = 0; it < 4; ++it) {
        int col = lr + it * 16;     // tile col -> T row
        ushort4 o;
        o.x = f2bf(t[lc4 + 0][col]); o.y = f2bf(t[lc4 + 1][col]);
        o.z = f2bf(t[lc4 + 2][col]); o.w = f2bf(t[lc4 + 3][col]);
        *reinterpret_cast<ushort4*>(T + (size_t)(c0 + col) * Dd + r0 + lc4) = o;
    }
}

// ---------------------------------------------------------------------------
// bf16 MFMA GEMM, T1+T2+T3+T4+T5 structure:
//   BM=128, BN=256, BK=64; 512 threads = 8 waves (2M x 4N), 64x64 per wave.
//   Triple-buffered LDS (144 KB), 2-deep prefetch, counted vmcnt(6).
//   4 phases per K-tile: {ds_read subtile | issue stage loads} -> barrier ->
//   setprio(1) 8 MFMA setprio(0) -> barrier.  Stage uses inverse-swizzled
//   GLOBAL source + linear LDS dest; reads swizzle (rule #21, T2):
//   seg_phys = seg_log ^ (row&7)  -> each quarter-wave puts exactly 2 lanes
//   per bank-quad (2-way = free, m136).
// QKV=1: N=3072 fused (Wq|Wk|Wv), bf16 out, phi on Q,K. QKV=0: N=1024, f32.
// ---------------------------------------------------------------------------
template<int QKV>
__global__ __launch_bounds__(512, 1)
void gemm_8ph(const unsigned short* __restrict__ A, const unsigned short* __restrict__ BT,
              float* __restrict__ outF, unsigned short* __restrict__ oQ,
              unsigned short* __restrict__ oK, unsigned short* __restrict__ oV) {
    constexpr int Kd  = 1024;
    constexpr int BK  = 64;
    constexpr int NT  = Kd / BK;           // 16 K-tiles
    constexpr int GX  = QKV ? 12 : 4;      // N / 256
    constexpr int NWG = GX * 64;
    constexpr int BUFSZ = (128 + 256) * BK;   // elems per buffer (A 8192 + B 16384)

    __shared__ __align__(16) unsigned short lds[3 * BUFSZ];   // 144 KB

    // T1: bijective XCD swizzle (NWG % 8 == 0)
    const int wg0 = blockIdx.x;
    const int wg  = (wg0 & 7) * (NWG >> 3) + (wg0 >> 3);
    const int by = wg & 63, bx = wg >> 6;  // consecutive wg share the B panel
    const int row0 = by * 128;
    const int col0 = bx * 256;

    const int tid  = threadIdx.x;
    const int lane = tid & 63;
    const int wave = tid >> 6;
    const int wm = (wave >> 2) * 64;       // wave M offset (0,64)
    const int wn = (wave & 3) * 64;        // wave N offset (0..192)
    const int fr = lane & 15;
    const int hi = lane >> 4;

    f32x4 acc[4][4];
#pragma unroll
    for (int mf = 0; mf < 4; ++mf)
#pragma unroll
        for (int nf = 0; nf < 4; ++nf) acc[mf][nf] = (f32x4){0.f, 0.f, 0.f, 0.f};

    // one 16B staging load; l in 0..5 (literal at every call site)
    auto stage1 = [&](int sel, int kt, int l) {
        unsigned short* base = &lds[sel * BUFSZ];
        int seg = l * 512 + tid;                      // 0..3071
        if (l < 2) {                                  // A: segs 0..1023
            int row = seg >> 3, sp = seg & 7;
            int gcol = kt + ((sp ^ (row & 7)) << 3);  // inverse-swizzled source
            __builtin_amdgcn_global_load_lds(
                (const __attribute__((address_space(1))) void*)(A + (size_t)(row0 + row) * Kd + gcol),
                (__attribute__((address_space(3))) void*)(base + seg * 8), 16, 0, 0);
        } else {                                      // B: segs 0..2047
            int bseg = seg - 1024;
            int row = bseg >> 3, sp = bseg & 7;
            int gcol = kt + ((sp ^ (row & 7)) << 3);
            __builtin_amdgcn_global_load_lds(
                (const __attribute__((address_space(1))) void*)(BT + (size_t)(col0 + row) * Kd + gcol),
                (__attribute__((address_space(3))) void*)(base + 8192 + bseg * 8), 16, 0, 0);
        }
    };
    // swizzled fragment reads (row multiple of 16 => row&7 == fr&7)
    auto lda = [&](const unsigned short* bufA, int mf, int ks) {
        int row = wm + mf * 16 + fr;
        int sp = ((ks << 2) | hi) ^ (row & 7);
        return *reinterpret_cast<const bf16x8*>(bufA + row * 64 + sp * 8);
    };
    auto ldb = [&](const unsigned short* bufB, int nf, int ks) {
        int row = wn + nf * 16 + fr;
        int sp = ((ks << 2) | hi) ^ (row & 7);
        return *reinterpret_cast<const bf16x8*>(bufB + row * 64 + sp * 8);
    };

    // prologue: stage tiles 0 and 1
#pragma unroll
    for (int l = 0; l < 6; ++l) stage1(0, 0, l);
#pragma unroll
    for (int l = 0; l < 6; ++l) stage1(1, BK, l);

    int selc = 0;
    for (int t = 0; t < NT; ++t) {
        // ---- correctness-critical: drain tile t's 6 loads, keep t+1's in flight
        if (t < NT - 1) { asm volatile("s_waitcnt vmcnt(6)" ::: "memory"); }
        else            { asm volatile("s_waitcnt vmcnt(0)" ::: "memory"); }
        __builtin_amdgcn_sched_barrier(0);
        __builtin_amdgcn_s_barrier();
        __builtin_amdgcn_sched_barrier(0);

        const unsigned short* bufA = &lds[selc * BUFSZ];
        const unsigned short* bufB = bufA + 8192;
        int sels = selc + 2; if (sels >= 3) sels -= 3;
        const bool st = (t + 2 < NT);
        const int kt2 = (t + 2) * BK;

        bf16x8 afr[4], b0, b1;

#define GEMM_PH_TAIL(MF_NFA, MF_NFB)                                           \
        __builtin_amdgcn_sched_barrier(0);                                     \
        __builtin_amdgcn_s_barrier();                                          \
        __builtin_amdgcn_sched_barrier(0);                                     \
        __builtin_amdgcn_s_setprio(1);                                         \
        _Pragma("unroll")                                                      \
        for (int mf = 0; mf < 4; ++mf) {                                       \
            acc[mf][MF_NFA] = __builtin_amdgcn_mfma_f32_16x16x32_bf16(afr[mf], b0, acc[mf][MF_NFA], 0, 0, 0); \
            acc[mf][MF_NFB] = __builtin_amdgcn_mfma_f32_16x16x32_bf16(afr[mf], b1, acc[mf][MF_NFB], 0, 0, 0); \
        }                                                                      \
        __builtin_amdgcn_s_setprio(0);                                         \
        __builtin_amdgcn_sched_barrier(0);                                     \
        __builtin_amdgcn_s_barrier();                                          \
        __builtin_amdgcn_sched_barrier(0);

        // ---- phase 0: a@ks0, b0,b1@ks0, stage l=0,1
        afr[0] = lda(bufA, 0, 0); afr[1] = lda(bufA, 1, 0);
        afr[2] = lda(bufA, 2, 0); afr[3] = lda(bufA, 3, 0);
        b0 = ldb(bufB, 0, 0); b1 = ldb(bufB, 1, 0);
        if (st) { stage1(sels, kt2, 0); stage1(sels, kt2, 1); }
        GEMM_PH_TAIL(0, 1)

        // ---- phase 1: b2,b3@ks0, stage l=2,3
        b0 = ldb(bufB, 2, 0); b1 = ldb(bufB, 3, 0);
        if (st) { stage1(sels, kt2, 2); stage1(sels, kt2, 3); }
        GEMM_PH_TAIL(2, 3)

        // ---- phase 2: a@ks1, b0,b1@ks1, stage l=4
        afr[0] = lda(bufA, 0, 1); afr[1] = lda(bufA, 1, 1);
        afr[2] = lda(bufA, 2, 1); afr[3] = lda(bufA, 3, 1);
        b0 = ldb(bufB, 0, 1); b1 = ldb(bufB, 1, 1);
        if (st) { stage1(sels, kt2, 4); }
        GEMM_PH_TAIL(0, 1)

        // ---- phase 3: b2,b3@ks1, stage l=5
        b0 = ldb(bufB, 2, 1); b1 = ldb(bufB, 3, 1);
        if (st) { stage1(sels, kt2, 5); }
        GEMM_PH_TAIL(2, 3)

#undef GEMM_PH_TAIL
        selc = (selc == 2) ? 0 : selc + 1;
    }

    // ---- epilogue: D[row = wm+mf*16+hi*4+r][col = wn+nf*16+fr]
    if (QKV) {
        const int sel = col0 >> 10;        // 0=Q,1=K,2=V
        unsigned short* ob = (sel == 0) ? oQ : (sel == 1) ? oK : oV;
        const bool phi = (sel < 2);
        const int ncol0 = col0 & 1023;
#pragma unroll
        for (int mf = 0; mf < 4; ++mf)
#pragma unroll
            for (int nf = 0; nf < 4; ++nf)
#pragma unroll
                for (int r = 0; r < 4; ++r) {
                    int orow = row0 + wm + mf * 16 + hi * 4 + r;
                    int ocol = ncol0 + wn + nf * 16 + fr;
                    float v = acc[mf][nf][r];
                    if (phi) v = (v > 0.f) ? (v + 1.f) : __expf(v);
                    ob[(size_t)orow * Dd + ocol] = f2bf(v);
                }
    } else {
#pragma unroll
        for (int mf = 0; mf < 4; ++mf)
#pragma unroll
            for (int nf = 0; nf < 4; ++nf)
#pragma unroll
                for (int r = 0; r < 4; ++r) {
                    int orow = row0 + wm + mf * 16 + hi * 4 + r;
                    int ocol = col0 + wn + nf * 16 + fr;
                    outF[(size_t)orow * Dd + ocol] = acc[mf][nf][r];
                }
    }
}

// ---------------------------------------------------------------------------
// chunk_sums (MFMA): CS'[e][d] = sum_j V[j][e]*K[j][d]  (bf16 out)
//                    CZ[d]     = sum_j K[j][d]          (fp32)
// ---------------------------------------------------------------------------
__global__ __launch_bounds__(256)
void chunk_sums_mfma(const unsigned short* __restrict__ Kb, const unsigned short* __restrict__ Vb,
                     unsigned short* __restrict__ CSb, float* __restrict__ CZ) {
    const int blk = blockIdx.x;
    const int c  = blk & (NCc - 1);
    const int bh = blk >> 5;
    const int b  = bh >> 4;
    const int h  = bh & 15;
    const int tid  = threadIdx.x;
    const int wave = tid >> 6, lane = tid & 63;
    const int lo = lane & 15, hi = lane >> 4;
    const int wr = (wave >> 1) * 32, wc = (wave & 1) * 32;

    __shared__ __align__(16) unsigned short Kt[64][72];
    __shared__ __align__(16) unsigned short Vt[64][72];

    const size_t rowbase = ((size_t)b * SEQ + c * Cc) * Dd + (size_t)h * DHh;

#pragma unroll
    for (int it = 0; it < 2; ++it) {
        int idx = tid + it * 256;
        int r = idx >> 3, c8 = (idx & 7) * 8;
        u16x8 kv = *reinterpret_cast<const u16x8*>(Kb + rowbase + (size_t)r * Dd + c8);
        u16x8 vv = *reinterpret_cast<const u16x8*>(Vb + rowbase + (size_t)r * Dd + c8);
#pragma unroll
        for (int q = 0; q < 8; ++q) {
            int d = c8 + q;
            int sc = swz(d, r);
            Kt[d][sc] = kv[q];
            Vt[d][sc] = vv[q];
        }
    }
    __syncthreads();

    f32x4 acc[2][2];
#pragma unroll
    for (int mf = 0; mf < 2; ++mf)
#pragma unroll
        for (int nf = 0; nf < 2; ++nf) acc[mf][nf] = (f32x4){0.f, 0.f, 0.f, 0.f};

#pragma unroll
    for (int kb = 0; kb < 2; ++kb) {
        const int ko = kb * 32 + hi * 8;
        bf16x8 av[2], bk[2];
#pragma unroll
        for (int mf = 0; mf < 2; ++mf) {
            int row = wr + mf * 16 + lo;
            av[mf] = *reinterpret_cast<const bf16x8*>(&Vt[row][swz(row, ko)]);
        }
#pragma unroll
        for (int nf = 0; nf < 2; ++nf) {
            int row = wc + nf * 16 + lo;
            bk[nf] = *reinterpret_cast<const bf16x8*>(&Kt[row][swz(row, ko)]);
        }
#pragma unroll
        for (int mf = 0; mf < 2; ++mf)
#pragma unroll
            for (int nf = 0; nf < 2; ++nf)
                acc[mf][nf] = __builtin_amdgcn_mfma_f32_16x16x32_bf16(av[mf], bk[nf], acc[mf][nf], 0, 0, 0);
    }

    if (tid < DHh) {
        float s = 0.f;
#pragma unroll
        for (int e8 = 0; e8 < 8; ++e8) {
            u16x8 k8 = *reinterpret_cast<const u16x8*>(&Kt[tid][e8 * 8]);
#pragma unroll
            for (int q = 0; q < 8; ++q) s += bf2f(k8[q]);
        }
        CZ[((size_t)bh * NCc + c) * DHh + tid] = s;
    }

    unsigned short* csb = CSb + ((size_t)bh * NCc + c) * (DHh * DHh);
#pragma unroll
    for (int mf = 0; mf < 2; ++mf)
#pragma unroll
        for (int nf = 0; nf < 2; ++nf)
#pragma unroll
            for (int r = 0; r < 4; ++r) {
                int e = wr + mf * 16 + hi * 4 + r;
                int d = wc + nf * 16 + lo;
                csb[e * DHh + d] = f2bf(acc[mf][nf][r]);
            }
}

// ---------------------------------------------------------------------------
// exclusive prefix scan over chunks (CS bf16 in-place, CZ fp32 in-place)
// ---------------------------------------------------------------------------
__global__ __launch_bounds__(256)
void chunk_scan2(unsigned short* __restrict__ CSb, float* __restrict__ CZ) {
    const int bh = blockIdx.x >> 3;
    const int sl = blockIdx.x & 7;
    const int tid = threadIdx.x;
    const int pos = sl * 512 + tid * 2;
    float a0 = 0.f, a1 = 0.f, accz = 0.f;

    for (int c = 0; c < NCc; ++c) {
        unsigned int* p = reinterpret_cast<unsigned int*>(
            CSb + ((size_t)bh * NCc + c) * (DHh * DHh) + pos);
        unsigned int cur = *p;
        *p = (unsigned)f2bf(a0) | ((unsigned)f2bf(a1) << 16);
        a0 += bf2f((unsigned short)(cur & 0xffff));
        a1 += bf2f((unsigned short)(cur >> 16));
        if (sl == 0 && tid < DHh) {
            float* pz = CZ + ((size_t)bh * NCc + c) * DHh + tid;
            float z = *pz; *pz = accz; accz += z;
        }
    }
}

// ---------------------------------------------------------------------------
// chunk_out (MFMA): O = (mask(QK^T)@V + Q@S_prev) / (q.z_prev + rowsum + eps)
// ---------------------------------------------------------------------------
__global__ __launch_bounds__(256)
void chunk_out_mfma(const unsigned short* __restrict__ Qb, const unsigned short* __restrict__ Kb,
                    const unsigned short* __restrict__ Vb, const unsigned short* __restrict__ CSb,
                    const float* __restrict__ CZ, unsigned short* __restrict__ Ob) {
    const int blk = blockIdx.x;
    const int c  = blk & (NCc - 1);
    const int bh = blk >> 5;
    const int b  = bh >> 4;
    const int h  = bh & 15;
    const int tid  = threadIdx.x;
    const int wave = tid >> 6, lane = tid & 63;
    const int lo = lane & 15, hi = lane >> 4;
    const int wr = (wave >> 1) * 32, wc = (wave & 1) * 32;

    __shared__ __align__(16) unsigned short Qs[64][72];
    __shared__ __align__(16) unsigned short KP[64][72];   // K, then P
    __shared__ __align__(16) unsigned short Ss[64][72];   // S_prev' (CS scanned)
    __shared__ __align__(16) unsigned short Vt[64][72];   // V transposed, swizzled
    __shared__ float zsL[DHh];
    __shared__ float rowp[64][2];
    __shared__ float denL[64];

    const size_t rowbase = ((size_t)b * SEQ + c * Cc) * Dd + (size_t)h * DHh;
    const unsigned short* csb = CSb + ((size_t)bh * NCc + c) * (DHh * DHh);

#pragma unroll
    for (int it = 0; it < 2; ++it) {
        int idx = tid + it * 256;
        int r = idx >> 3, c8 = (idx & 7) * 8;
        u16x8 qv = *reinterpret_cast<const u16x8*>(Qb + rowbase + (size_t)r * Dd + c8);
        u16x8 kv = *reinterpret_cast<const u16x8*>(Kb + rowbase + (size_t)r * Dd + c8);
        u16x8 vv = *reinterpret_cast<const u16x8*>(Vb + rowbase + (size_t)r * Dd + c8);
        u16x8 sv = *reinterpret_cast<const u16x8*>(csb + idx * 8);
        *reinterpret_cast<u16x8*>(&Qs[r][c8]) = qv;
        *reinterpret_cast<u16x8*>(&KP[r][c8]) = kv;
        *reinterpret_cast<u16x8*>(&Ss[r][c8]) = sv;
#pragma unroll
        for (int q = 0; q < 8; ++q) {
            int d = c8 + q;
            Vt[d][swz(d, r)] = vv[q];
        }
    }
    if (tid < DHh) zsL[tid] = CZ[((size_t)bh * NCc + c) * DHh + tid];
    __syncthreads();

    f32x4 accs[2][2], accO[2][2];
#pragma unroll
    for (int mf = 0; mf < 2; ++mf)
#pragma unroll
        for (int nf = 0; nf < 2; ++nf) {
            accs[mf][nf] = (f32x4){0.f, 0.f, 0.f, 0.f};
            accO[mf][nf] = (f32x4){0.f, 0.f, 0.f, 0.f};
        }

#pragma unroll
    for (int kb = 0; kb < 2; ++kb) {
        const int ko = kb * 32 + hi * 8;
        bf16x8 aq[2], bk[2], bs[2];
#pragma unroll
        for (int mf = 0; mf < 2; ++mf)
            aq[mf] = *reinterpret_cast<const bf16x8*>(&Qs[wr + mf * 16 + lo][ko]);
#pragma unroll
        for (int nf = 0; nf < 2; ++nf) {
            bk[nf] = *reinterpret_cast<const bf16x8*>(&KP[wc + nf * 16 + lo][ko]);
            bs[nf] = *reinterpret_cast<const bf16x8*>(&Ss[wc + nf * 16 + lo][ko]);
        }
#pragma unroll
        for (int mf = 0; mf < 2; ++mf)
#pragma unroll
            for (int nf = 0; nf < 2; ++nf) {
                accs[mf][nf] = __builtin_amdgcn_mfma_f32_16x16x32_bf16(aq[mf], bk[nf], accs[mf][nf], 0, 0, 0);
                accO[mf][nf] = __builtin_amdgcn_mfma_f32_16x16x32_bf16(aq[mf], bs[nf], accO[mf][nf], 0, 0, 0);
            }
    }

    // mask + rowsum (shfl over the 16-lane lo-group)
#pragma unroll
    for (int mf = 0; mf < 2; ++mf)
#pragma unroll
        for (int r = 0; r < 4; ++r) {
            int i = wr + mf * 16 + hi * 4 + r;
            float s = 0.f;
#pragma unroll
            for (int nf = 0; nf < 2; ++nf) {
                int j = wc + nf * 16 + lo;
                float v = (j <= i) ? accs[mf][nf][r] : 0.f;
                accs[mf][nf][r] = v;
                s += v;
            }
            s += __shfl_xor(s, 1); s += __shfl_xor(s, 2);
            s += __shfl_xor(s, 4); s += __shfl_xor(s, 8);
            if (lo == 0) rowp[i][wave & 1] = s;
        }
    __syncthreads();

    // P (bf16) -> KP buffer; den on 64 threads
#pragma unroll
    for (int mf = 0; mf < 2; ++mf)
#pragma unroll
        for (int nf = 0; nf < 2; ++nf)
#pragma unroll
            for (int r = 0; r < 4; ++r)
                KP[wr + mf * 16 + hi * 4 + r][wc + nf * 16 + lo] = f2bf(accs[mf][nf][r]);
    if (tid < 64) {
        float d = 0.f;
#pragma unroll
        for (int e8 = 0; e8 < 8; ++e8) {
            u16x8 q8 = *reinterpret_cast<const u16x8*>(&Qs[tid][e8 * 8]);
#pragma unroll
            for (int q = 0; q < 8; ++q) d += bf2f(q8[q]) * zsL[e8 * 8 + q];
        }
        denL[tid] = d + rowp[tid][0] + rowp[tid][1] + EPSf;
    }
    __syncthreads();

    // intra: accO += P V
#pragma unroll
    for (int kb = 0; kb < 2; ++kb) {
        const int ko = kb * 32 + hi * 8;
        bf16x8 ap[2], bv[2];
#pragma unroll
        for (int mf = 0; mf < 2; ++mf)
            ap[mf] = *reinterpret_cast<const bf16x8*>(&KP[wr + mf * 16 + lo][ko]);
#pragma unroll
        for (int nf = 0; nf < 2; ++nf) {
            int row = wc + nf * 16 + lo;
            bv[nf] = *reinterpret_cast<const bf16x8*>(&Vt[row][swz(row, ko)]);
        }
#pragma unroll
        for (int mf = 0; mf < 2; ++mf)
#pragma unroll
            for (int nf = 0; nf < 2; ++nf)
                accO[mf][nf] = __builtin_amdgcn_mfma_f32_16x16x32_bf16(ap[mf], bv[nf], accO[mf][nf], 0, 0, 0);
    }

    // epilogue
#pragma unroll
    for (int mf = 0; mf < 2; ++mf)
#pragma unroll
        for (int r = 0; r < 4; ++r) {
            int i = wr + mf * 16 + hi * 4 + r;
            float inv = 1.0f / denL[i];
#pragma unroll
            for (int nf = 0; nf < 2; ++nf) {
                int e = wc + nf * 16 + lo;
                Ob[rowbase + (size_t)i * Dd + e] = f2bf(accO[mf][nf][r] * inv);
            }
        }
}

// ---------------------------------------------------------------------------
extern "C" void kernel_launch(void* const* d_in, const int* in_sizes, int n_in,
                              void* d_out, int out_size, void* d_ws, size_t ws_size,
                              hipStream_t stream) {
    const float* x  = (const float*)d_in[0];
    const float* Wq = (const float*)d_in[1];
    const float* Wk = (const float*)d_in[2];
    const float* Wv = (const float*)d_in[3];
    const float* Wo = (const float*)d_in[4];

    const size_t NMD = (size_t)Mm * Dd;       // 8388608
    const size_t NW  = (size_t)Dd * Dd;       // 1048576
    unsigned short* xb  = (unsigned short*)d_ws;           // 16 MB
    unsigned short* WT  = xb + NMD;                        // 8 MB (Wq^T|Wk^T|Wv^T|Wo^T)
    unsigned short* Qb  = WT + 4 * NW;                     // 16 MB
    unsigned short* Kb  = Qb + NMD;                        // 16 MB
    unsigned short* Vb  = Kb + NMD;                        // 16 MB
    unsigned short* Obf = Vb + NMD;                        // 16 MB
    unsigned short* CSb = Obf + NMD;                       // 16.8 MB (bf16, scanned in-place)
    float* CZ = (float*)(CSb + (size_t)Bb * Hh * NCc * DHh * DHh); // 0.5 MB

    // casts / transposes
    cast_bf16<<<(int)(NMD / 8 + 255) / 256, 256, 0, stream>>>(x, xb, (int)(NMD / 8));
    transpose_cast_w<<<dim3(16, 16, 4), 256, 0, stream>>>(Wq, Wk, Wv, Wo, WT);

    // fused QKV projection: N=3072 over contiguous (Wq^T|Wk^T|Wv^T); phi on Q,K
    gemm_8ph<1><<<12 * 64, 512, 0, stream>>>(xb, WT, nullptr, Qb, Kb, Vb);

    // chunked linear attention (MFMA)
    chunk_sums_mfma<<<Bb * Hh * NCc, 256, 0, stream>>>(Kb, Vb, CSb, CZ);
    chunk_scan2<<<Bb * Hh * 8, 256, 0, stream>>>(CSb, CZ);
    chunk_out_mfma<<<Bb * Hh * NCc, 256, 0, stream>>>(Qb, Kb, Vb, CSb, CZ, Obf);

    // output projection -> d_out (fp32)
    gemm_8ph<0><<<4 * 64, 512, 0, stream>>>(Obf, WT + 3 * NW, (float*)d_out, nullptr, nullptr, nullptr);
}